// Round 1
// baseline (452.889 us; speedup 1.0000x reference)
//
#include <hip/hip_runtime.h>
#include <math.h>

// Problem constants
#define BB 2
#define SS 2048
#define EE 2048
#define HH 16
#define DD 128
#define FF 6144   // 3*E

typedef __attribute__((ext_vector_type(8))) short short8;
typedef __attribute__((ext_vector_type(4))) float floatx4;

static __device__ __forceinline__ unsigned short f2bf(float x) {
  unsigned u = __float_as_uint(x);
  u += 0x7fffu + ((u >> 16) & 1u);
  return (unsigned short)(u >> 16);
}
static __device__ __forceinline__ float bf2f(unsigned short h) {
  return __uint_as_float((unsigned)h << 16);
}

#define GLOAD_LDS16(gp, lp)                                       \
  __builtin_amdgcn_global_load_lds(                               \
      (const __attribute__((address_space(1))) void*)(gp),        \
      (__attribute__((address_space(3))) void*)(lp), 16, 0, 0)

// ---------------------------------------------------------------------------
// fp32 -> bf16 cast (float4 in, ushort4 out)
// ---------------------------------------------------------------------------
__global__ __launch_bounds__(256) void cast_f32_bf16(
    const float* __restrict__ in, unsigned short* __restrict__ out, int n4) {
  const int i = blockIdx.x * 256 + threadIdx.x;
  if (i >= n4) return;
  const float4 v = ((const float4*)in)[i];
  ushort4 o;
  o.x = f2bf(v.x); o.y = f2bf(v.y); o.z = f2bf(v.z); o.w = f2bf(v.w);
  ((ushort4*)out)[i] = o;
}

static __device__ __forceinline__ void store_out(float* p, float v) { *p = v; }
static __device__ __forceinline__ void store_out(unsigned short* p, float v) {
  *p = f2bf(v);
}

// ---------------------------------------------------------------------------
// bf16 MFMA GEMM, double-buffered 128^2 (kept for the out-projection, where
// N=2048 gives only 128 workgroups of the 256^2 kernel -> half the CUs idle).
// ---------------------------------------------------------------------------
template <typename OutT>
__global__ __launch_bounds__(256) void gemm_bf16_mfma(
    const unsigned short* __restrict__ A, const unsigned short* __restrict__ Bt,
    const float* __restrict__ bias, OutT* __restrict__ C,
    int M, int N, int K) {
  __shared__ unsigned short As[2][128][32];
  __shared__ unsigned short Bs[2][128][32];
  const int tid = threadIdx.x;
  const int L = tid & 63;
  const int w = tid >> 6;
  const int m0 = blockIdx.y * 128;
  const int n0 = blockIdx.x * 128;

  const int i0 = w * 2;
  const int lrow = L >> 2;
  const int lcol = (L & 3) * 8;
  const size_t a_off0 = (size_t)(m0 + (i0 + 0) * 16 + lrow) * K + lcol;
  const size_t a_off1 = (size_t)(m0 + (i0 + 1) * 16 + lrow) * K + lcol;
  const size_t b_off0 = (size_t)(n0 + (i0 + 0) * 16 + lrow) * K + lcol;
  const size_t b_off1 = (size_t)(n0 + (i0 + 1) * 16 + lrow) * K + lcol;

  const int wr = (w >> 1) * 64;
  const int wc = (w & 1) * 64;
  const int lane16 = L & 15;
  const int quad = L >> 4;

  floatx4 acc[4][4] = {};

  GLOAD_LDS16(A + a_off0, &As[0][(i0 + 0) * 16][0]);
  GLOAD_LDS16(A + a_off1, &As[0][(i0 + 1) * 16][0]);
  GLOAD_LDS16(Bt + b_off0, &Bs[0][(i0 + 0) * 16][0]);
  GLOAD_LDS16(Bt + b_off1, &Bs[0][(i0 + 1) * 16][0]);

  for (int k0 = 0; k0 < K; k0 += 32) {
    const int cur = (k0 >> 5) & 1;
    __syncthreads();
    if (k0 + 32 < K) {
      const int nxt = cur ^ 1;
      GLOAD_LDS16(A + a_off0 + k0 + 32, &As[nxt][(i0 + 0) * 16][0]);
      GLOAD_LDS16(A + a_off1 + k0 + 32, &As[nxt][(i0 + 1) * 16][0]);
      GLOAD_LDS16(Bt + b_off0 + k0 + 32, &Bs[nxt][(i0 + 0) * 16][0]);
      GLOAD_LDS16(Bt + b_off1 + k0 + 32, &Bs[nxt][(i0 + 1) * 16][0]);
    }

    short8 a[4], b[4];
#pragma unroll
    for (int mi = 0; mi < 4; ++mi)
      a[mi] = *(const short8*)(&As[cur][wr + mi * 16 + lane16][quad * 8]);
#pragma unroll
    for (int ni = 0; ni < 4; ++ni)
      b[ni] = *(const short8*)(&Bs[cur][wc + ni * 16 + lane16][quad * 8]);
#pragma unroll
    for (int mi = 0; mi < 4; ++mi)
#pragma unroll
      for (int ni = 0; ni < 4; ++ni)
        acc[mi][ni] = __builtin_amdgcn_mfma_f32_16x16x32_bf16(
            a[mi], b[ni], acc[mi][ni], 0, 0, 0);
  }

#pragma unroll
  for (int ni = 0; ni < 4; ++ni) {
    const int col = n0 + wc + ni * 16 + lane16;
    const float bv = bias[col];
#pragma unroll
    for (int mi = 0; mi < 4; ++mi) {
      const int row = m0 + wr + mi * 16 + quad * 4;
#pragma unroll
      for (int r = 0; r < 4; ++r)
        store_out(&C[(size_t)(row + r) * N + col], acc[mi][ni][r] + bv);
    }
  }
}

// ---------------------------------------------------------------------------
// 256x256 8-phase bf16 GEMM (T2 st_16x32 swizzle + T3/T4 counted vmcnt + T5).
//
// Geometry: BM=BN=256, BK=64, 512 thr = 8 waves (2M x 4N), per-wave C 128x64.
// LDS: 2 buf x (A 256x64 + B 256x64) bf16 = 128 KiB, stored as 16x32-element
// subtiles (1024 B each) with the st_16x32 XOR swizzle (col bit4 ^= row bit3).
// Rows are PERMUTED so staging order == first-use order:
//   A LDS rows: [ah0wm0 | ah0wm1 | ah1wm0 | ah1wm1]  (ah = 64-row半 of wave)
//   B LDS rows: [bh0wn0 wn1 | bh0wn2 wn3 | bh1wn0 wn1 | bh1wn2 wn3]
// Stage issue order per K-tile (2 gload_lds per phase, 8 total):
//   P0: A win0,1 (P0-need)  P1: B win0,1 (P0-need)
//   P2: B win2,3 (P1-need)  P3: A win2,3 (P2-need)
// vmcnt(4) at every phase end => each group provably landed >=2 phases before
// its first ds_read; never drained to 0 in the main loop (T4).
// Phase MFMA quadrants: P0:(A0,B0) P1:(A0,B1) P2:(A1,B1) P3:(A1,B0); only A
// needs reload (one reg set), B keeps two sets -> ~192 operand+acc VGPRs.
// ---------------------------------------------------------------------------
template <typename OutT>
__global__ __launch_bounds__(512, 2) void gemm256_8ph(
    const unsigned short* __restrict__ A, const unsigned short* __restrict__ Bt,
    const float* __restrict__ bias, OutT* __restrict__ C,
    int M, int N, int K) {
  __shared__ __align__(16) unsigned short As[2][16384];
  __shared__ __align__(16) unsigned short Bs[2][16384];

  const int tid = threadIdx.x;
  const int w = tid >> 6;
  const int L = tid & 63;
  const int lane16 = L & 15;
  const int quad = L >> 4;
  const int wm = w >> 2;   // 0..1
  const int wn = w & 3;    // 0..3

  // XCD-aware bijective swizzle (gridDim.x % 8 == 0 for our shapes)
  const int nbx = N >> 8;
  const int q8 = gridDim.x >> 3;
  const int wg = (blockIdx.x & 7) * q8 + (blockIdx.x >> 3);
  const int bx = wg % nbx;
  const int by = wg / nbx;
  const int m0 = by << 8;
  const int n0 = bx << 8;

  // ---- staging source offsets (pre-swizzled global, rule #21) ----
  // Each stage instr = 8 KiB window = 4 row-groups; wave w owns subtile w.
  const int lA = ((w >> 1) << 4) + (L >> 2);  // low-6 LDS row within window
  const int scol = ((w & 1) << 5) + (((L & 3) * 8) ^ ((L & 32) ? 16 : 0));
  unsigned aoff[4], boff[4];
#pragma unroll
  for (int j = 0; j < 4; ++j) {
    const int ra = ((j & 1) << 7) | ((j >> 1) << 6) | lA;  // rhoA^-1
    aoff[j] = (unsigned)(m0 + ra) * (unsigned)K + scol;
    const int lB = j * 64 + lA;
    const int rB = (((lB >> 5) & 3) << 6) | (((lB >> 7) & 1) << 5) | (lB & 31);
    boff[j] = (unsigned)(n0 + rB) * (unsigned)K + scol;
  }
  const int ldst = w * 512;  // ushort offset of wave's subtile within window

  // ---- ds_read addressing ----
  // elem (ldsrow l, col c): ushort idx = ((l>>4)*2 + (c>>5))*512
  //                                      + (l&15)*32 + ((c&31) ^ ((l&8)<<1))
  const int sq = (quad * 8) ^ ((lane16 & 8) << 1);
  const int rbase = lane16 * 32 + sq;

  floatx4 acc[8][4] = {};

  // prologue: stage tile0 -> buf0 in gating order A0a A0b B0a B0b B1a B1b A1a A1b
  GLOAD_LDS16(A + aoff[0], &As[0][0 * 4096 + ldst]);
  GLOAD_LDS16(A + aoff[1], &As[0][1 * 4096 + ldst]);
  GLOAD_LDS16(Bt + boff[0], &Bs[0][0 * 4096 + ldst]);
  GLOAD_LDS16(Bt + boff[1], &Bs[0][1 * 4096 + ldst]);
  GLOAD_LDS16(Bt + boff[2], &Bs[0][2 * 4096 + ldst]);
  GLOAD_LDS16(Bt + boff[3], &Bs[0][3 * 4096 + ldst]);
  GLOAD_LDS16(A + aoff[2], &As[0][2 * 4096 + ldst]);
  GLOAD_LDS16(A + aoff[3], &As[0][3 * 4096 + ldst]);
  asm volatile("s_waitcnt vmcnt(4)" ::: "memory");
  __builtin_amdgcn_s_barrier();

  const int NT = K >> 6;
  short8 a[4][2], b0[2][2], b1[2][2];

  for (int t = 0; t < NT; ++t) {
    const int c = t & 1;
    const int nc = c ^ 1;
    const unsigned kn = (unsigned)(t + 1) << 6;
    const bool pf = (t + 1 < NT);
    const unsigned short* Ac = &As[c][0];
    const unsigned short* Bc = &Bs[c][0];

    // ---------------- P0: read A0(8)+B0(4); stage A win0,1; mfma (A0,B0)
#pragma unroll
    for (int i = 0; i < 4; ++i)
#pragma unroll
      for (int kk = 0; kk < 2; ++kk)
        a[i][kk] = *(const short8*)(Ac + ((wm * 4 + i) * 2 + kk) * 512 + rbase);
#pragma unroll
    for (int j = 0; j < 2; ++j)
#pragma unroll
      for (int kk = 0; kk < 2; ++kk)
        b0[j][kk] = *(const short8*)(Bc + ((wn * 2 + j) * 2 + kk) * 512 + rbase);
    if (pf) {
      GLOAD_LDS16(A + aoff[0] + kn, &As[nc][0 * 4096 + ldst]);
      GLOAD_LDS16(A + aoff[1] + kn, &As[nc][1 * 4096 + ldst]);
    }
    asm volatile("s_waitcnt lgkmcnt(8)" ::: "memory");
    __builtin_amdgcn_s_barrier();
    asm volatile("s_waitcnt lgkmcnt(0)" ::: "memory");
    __builtin_amdgcn_s_setprio(1);
#pragma unroll
    for (int i = 0; i < 4; ++i)
#pragma unroll
      for (int j = 0; j < 2; ++j)
#pragma unroll
        for (int kk = 0; kk < 2; ++kk)
          acc[i][j] = __builtin_amdgcn_mfma_f32_16x16x32_bf16(
              a[i][kk], b0[j][kk], acc[i][j], 0, 0, 0);
    __builtin_amdgcn_s_setprio(0);
    asm volatile("s_waitcnt vmcnt(4)" ::: "memory");
    __builtin_amdgcn_s_barrier();

    // ---------------- P1: read B1(4); stage B win0,1; mfma (A0,B1)
#pragma unroll
    for (int j = 0; j < 2; ++j)
#pragma unroll
      for (int kk = 0; kk < 2; ++kk)
        b1[j][kk] =
            *(const short8*)(Bc + ((8 + wn * 2 + j) * 2 + kk) * 512 + rbase);
    if (pf) {
      GLOAD_LDS16(Bt + boff[0] + kn, &Bs[nc][0 * 4096 + ldst]);
      GLOAD_LDS16(Bt + boff[1] + kn, &Bs[nc][1 * 4096 + ldst]);
    }
    __builtin_amdgcn_s_barrier();
    asm volatile("s_waitcnt lgkmcnt(0)" ::: "memory");
    __builtin_amdgcn_s_setprio(1);
#pragma unroll
    for (int i = 0; i < 4; ++i)
#pragma unroll
      for (int j = 0; j < 2; ++j)
#pragma unroll
        for (int kk = 0; kk < 2; ++kk)
          acc[i][2 + j] = __builtin_amdgcn_mfma_f32_16x16x32_bf16(
              a[i][kk], b1[j][kk], acc[i][2 + j], 0, 0, 0);
    __builtin_amdgcn_s_setprio(0);
    asm volatile("s_waitcnt vmcnt(4)" ::: "memory");
    __builtin_amdgcn_s_barrier();

    // ---------------- P2: read A1(8); stage B win2,3; mfma (A1,B1)
#pragma unroll
    for (int i = 0; i < 4; ++i)
#pragma unroll
      for (int kk = 0; kk < 2; ++kk)
        a[i][kk] =
            *(const short8*)(Ac + ((8 + wm * 4 + i) * 2 + kk) * 512 + rbase);
    if (pf) {
      GLOAD_LDS16(Bt + boff[2] + kn, &Bs[nc][2 * 4096 + ldst]);
      GLOAD_LDS16(Bt + boff[3] + kn, &Bs[nc][3 * 4096 + ldst]);
    }
    __builtin_amdgcn_s_barrier();
    asm volatile("s_waitcnt lgkmcnt(0)" ::: "memory");
    __builtin_amdgcn_s_setprio(1);
#pragma unroll
    for (int i = 0; i < 4; ++i)
#pragma unroll
      for (int j = 0; j < 2; ++j)
#pragma unroll
        for (int kk = 0; kk < 2; ++kk)
          acc[4 + i][2 + j] = __builtin_amdgcn_mfma_f32_16x16x32_bf16(
              a[i][kk], b1[j][kk], acc[4 + i][2 + j], 0, 0, 0);
    __builtin_amdgcn_s_setprio(0);
    asm volatile("s_waitcnt vmcnt(4)" ::: "memory");
    __builtin_amdgcn_s_barrier();

    // ---------------- P3: no reads; stage A win2,3; mfma (A1,B0)
    if (pf) {
      GLOAD_LDS16(A + aoff[2] + kn, &As[nc][2 * 4096 + ldst]);
      GLOAD_LDS16(A + aoff[3] + kn, &As[nc][3 * 4096 + ldst]);
    }
    __builtin_amdgcn_s_barrier();
    __builtin_amdgcn_s_setprio(1);
#pragma unroll
    for (int i = 0; i < 4; ++i)
#pragma unroll
      for (int j = 0; j < 2; ++j)
#pragma unroll
        for (int kk = 0; kk < 2; ++kk)
          acc[4 + i][j] = __builtin_amdgcn_mfma_f32_16x16x32_bf16(
              a[i][kk], b0[j][kk], acc[4 + i][j], 0, 0, 0);
    __builtin_amdgcn_s_setprio(0);
    asm volatile("s_waitcnt vmcnt(4)" ::: "memory");
    __builtin_amdgcn_s_barrier();
  }

  // epilogue
#pragma unroll
  for (int ni = 0; ni < 4; ++ni) {
    const int col = n0 + wn * 64 + ni * 16 + lane16;
    const float bv = bias[col];
#pragma unroll
    for (int mi = 0; mi < 8; ++mi) {
      const int row = m0 + wm * 128 + mi * 16 + quad * 4;
#pragma unroll
      for (int r = 0; r < 4; ++r)
        store_out(&C[(size_t)(row + r) * N + col], acc[mi][ni][r] + bv);
    }
  }
}

// ---------------------------------------------------------------------------
// Rotary on bf16 qkv in place. qkv layout [B][S][3][H][D] bf16.
// ---------------------------------------------------------------------------
__global__ __launch_bounds__(256) void rotary_kernel(unsigned short* __restrict__ qkv) {
  const int idx = blockIdx.x * blockDim.x + threadIdx.x;
  const int d = idx & 63;
  const int h = (idx >> 6) & (HH - 1);
  const int s = (idx >> 10) & (SS - 1);
  const int b = idx >> 21;

  const float inv_freq = powf(10000.0f, -(float)d / 64.0f);
  const float freq = (float)s * inv_freq;
  const float c = cosf(freq);
  const float sn = sinf(freq);

  const size_t base = ((size_t)b * SS + s) * FF + h * DD + d;
  unsigned short* q = qkv + base;
  unsigned short* k = qkv + base + EE;

  const float q1 = bf2f(q[0]), q2 = bf2f(q[64]);
  q[0]  = f2bf(q1 * c - q2 * sn);
  q[64] = f2bf(q2 * c + q1 * sn);
  const float k1 = bf2f(k[0]), k2 = bf2f(k[64]);
  k[0]  = f2bf(k1 * c - k2 * sn);
  k[64] = f2bf(k2 * c + k1 * sn);
}

// ---------------------------------------------------------------------------
// V transpose: qkv V slab [b][s][h][d] -> vt [b*H+h][d][s]   (bf16)
// ---------------------------------------------------------------------------
__global__ __launch_bounds__(256) void transpose_v(
    const unsigned short* __restrict__ qkv, unsigned short* __restrict__ vt) {
  __shared__ unsigned short T[64][72];
  const int t = threadIdx.x;
  const int s0 = blockIdx.x * 64;
  const int d0 = blockIdx.y * 64;
  const int bh = blockIdx.z;
  const int b = bh >> 4, h = bh & 15;
  {
    const int r = t >> 2, c = (t & 3) * 16;
    const unsigned short* src =
        qkv + ((size_t)b * SS + s0 + r) * FF + 2 * EE + h * DD + d0 + c;
    const uint4 u0 = *(const uint4*)src;
    const uint4 u1 = *(const uint4*)(src + 8);
    *(uint4*)&T[r][c] = u0;
    *(uint4*)&T[r][c + 8] = u1;
  }
  __syncthreads();
  {
    const int rr = t >> 2, cc = (t & 3) * 16;
    unsigned short vals[16];
#pragma unroll
    for (int j = 0; j < 16; ++j) vals[j] = T[cc + j][rr];
    unsigned short* dst =
        vt + (size_t)bh * DD * SS + (size_t)(d0 + rr) * SS + s0 + cc;
    *(uint4*)dst = *(uint4*)&vals[0];
    *(uint4*)(dst + 8) = *(uint4*)&vals[8];
  }
}

// ---------------------------------------------------------------------------
// MFMA flash attention, causal — S^T/O^T, dbuf K/V, paired q-tiles,
// XCD-co-located grid (unchanged from previous round).
// ---------------------------------------------------------------------------
#define ATQ 128
#define ATK 32
#define SPAD 40
#define NQT (SS / ATQ)

__global__ __launch_bounds__(256, 2) void attn_mfma(
    const unsigned short* __restrict__ qkv,
    const unsigned short* __restrict__ vt,
    unsigned short* __restrict__ ctx) {
  __shared__ __align__(16) unsigned short Ksh[2][ATK * DD];
  __shared__ __align__(16) unsigned short Vsh[2][DD * ATK];
  __shared__ __align__(16) unsigned short Ssh[ATQ][SPAD];

  const int tid = threadIdx.x;
  const int L = tid & 63;
  const int w = tid >> 6;
  const int lane16 = L & 15;
  const int quad = L >> 4;

  const int flat = blockIdx.x;
  const int pi = flat >> 5;
  const int bh_lin = flat & 31;
  const int b = bh_lin >> 4;
  const int h = bh_lin & 15;
  const int bh = b * HH + h;
  const float scale = 0.08838834764831845f;

  size_t koff[2], voff[2];
  int kdst[2], vdst[2];
#pragma unroll
  for (int j = 0; j < 2; ++j) {
    const int ck = j * 256 + tid;
    const int kk = ck >> 4;
    const int cgk = (ck & 15) ^ (kk & 15);
    koff[j] = ((size_t)b * SS + kk) * FF + EE + h * DD + cgk * 8;
    kdst[j] = (j * 256 + w * 64) * 8;
    const int d = ck >> 2;
    const int cgv = (ck & 3) ^ (d & 3);
    voff[j] = (size_t)bh * DD * SS + (size_t)d * SS + cgv * 8;
    vdst[j] = kdst[j];
  }

#pragma unroll 1
  for (int phase = 0; phase < 2; ++phase) {
    const int qb = phase ? pi : (NQT - 1 - pi);
    const int q0 = qb * ATQ;

    short8 qf[2][4];
#pragma unroll
    for (int mi = 0; mi < 2; ++mi) {
      const int q = q0 + w * 32 + mi * 16 + lane16;
      const unsigned short* qp =
          qkv + ((size_t)b * SS + q) * FF + h * DD + quad * 8;
#pragma unroll
      for (int dc = 0; dc < 4; ++dc)
        qf[mi][dc] = *(const short8*)(qp + dc * 32);
    }

    floatx4 acc[8][2] = {};
    float m_i[2] = {-3.0e38f, -3.0e38f};
    float l_i[2] = {0.0f, 0.0f};

    const int nkt = 4 * qb + 4;
    const int mykt = 4 * qb + w;

#pragma unroll
    for (int j = 0; j < 2; ++j) {
      GLOAD_LDS16(qkv + koff[j], &Ksh[0][kdst[j]]);
      GLOAD_LDS16(vt + voff[j], &Vsh[0][vdst[j]]);
    }

    for (int kt = 0; kt < nkt; ++kt) {
      const int cur = kt & 1;
      __syncthreads();
      if (kt + 1 < nkt) {
        const size_t ka = (size_t)(kt + 1) * ATK * FF;
        const int va = (kt + 1) * ATK;
#pragma unroll
        for (int j = 0; j < 2; ++j) {
          GLOAD_LDS16(qkv + koff[j] + ka, &Ksh[cur ^ 1][kdst[j]]);
          GLOAD_LDS16(vt + voff[j] + va, &Vsh[cur ^ 1][vdst[j]]);
        }
      }
      if (kt > mykt) continue;
      const int k0 = kt * ATK;
      const unsigned short* Kc = Ksh[cur];
      const unsigned short* Vc = Vsh[cur];

      floatx4 st[2][2] = {};
#pragma unroll
      for (int kkt = 0; kkt < 2; ++kkt) {
        const unsigned short* krow = Kc + (kkt * 16 + lane16) * 128;
#pragma unroll
        for (int dc = 0; dc < 4; ++dc) {
          const short8 kf =
              *(const short8*)(krow + ((dc * 4 + quad) ^ lane16) * 8);
#pragma unroll
          for (int mi = 0; mi < 2; ++mi)
            st[kkt][mi] = __builtin_amdgcn_mfma_f32_16x16x32_bf16(
                kf, qf[mi][dc], st[kkt][mi], 0, 0, 0);
        }
      }

      const bool needmask = (kt == mykt);
#pragma unroll
      for (int mi = 0; mi < 2; ++mi) {
        const int q_glob = q0 + w * 32 + mi * 16 + lane16;
#pragma unroll
        for (int kkt = 0; kkt < 2; ++kkt) {
          const int kkb = k0 + kkt * 16 + quad * 4;
#pragma unroll
          for (int r = 0; r < 4; ++r) {
            float v = st[kkt][mi][r] * scale;
            if (needmask && (kkb + r) > q_glob) v = -3.0e38f;
            st[kkt][mi][r] = v;
          }
        }
      }

      float alpha[2];
#pragma unroll
      for (int mi = 0; mi < 2; ++mi) {
        float tm = -3.0e38f;
#pragma unroll
        for (int kkt = 0; kkt < 2; ++kkt)
#pragma unroll
          for (int r = 0; r < 4; ++r) tm = fmaxf(tm, st[kkt][mi][r]);
        tm = fmaxf(tm, __shfl_xor(tm, 16));
        tm = fmaxf(tm, __shfl_xor(tm, 32));
        const float mn = fmaxf(m_i[mi], tm);
        alpha[mi] = __expf(m_i[mi] - mn);
        m_i[mi] = mn;

        float rs = 0.0f;
#pragma unroll
        for (int kkt = 0; kkt < 2; ++kkt)
#pragma unroll
          for (int r = 0; r < 4; ++r) {
            const float p = __expf(st[kkt][mi][r] - mn);
            st[kkt][mi][r] = p;
            rs += p;
          }
        rs += __shfl_xor(rs, 16);
        rs += __shfl_xor(rs, 32);
        l_i[mi] = l_i[mi] * alpha[mi] + rs;

#pragma unroll
        for (int kkt = 0; kkt < 2; ++kkt) {
          ushort4 pk;
          pk.x = f2bf(st[kkt][mi][0]);
          pk.y = f2bf(st[kkt][mi][1]);
          pk.z = f2bf(st[kkt][mi][2]);
          pk.w = f2bf(st[kkt][mi][3]);
          *(ushort4*)(&Ssh[w * 32 + mi * 16 + lane16][kkt * 16 + quad * 4]) =
              pk;
        }
      }

#pragma unroll
      for (int dt = 0; dt < 8; ++dt)
#pragma unroll
        for (int mi = 0; mi < 2; ++mi)
#pragma unroll
          for (int r = 0; r < 4; ++r) acc[dt][mi][r] *= alpha[mi];

      short8 pa[2];
#pragma unroll
      for (int mi = 0; mi < 2; ++mi)
        pa[mi] = *(const short8*)(&Ssh[w * 32 + mi * 16 + lane16][quad * 8]);
      const int vpos = (quad ^ (lane16 & 3)) * 8;
#pragma unroll
      for (int dt = 0; dt < 8; ++dt) {
        const short8 vf =
            *(const short8*)(Vc + (dt * 16 + lane16) * 32 + vpos);
#pragma unroll
        for (int mi = 0; mi < 2; ++mi)
          acc[dt][mi] = __builtin_amdgcn_mfma_f32_16x16x32_bf16(
              vf, pa[mi], acc[dt][mi], 0, 0, 0);
      }
    }

#pragma unroll
    for (int mi = 0; mi < 2; ++mi) {
      const float inv = 1.0f / l_i[mi];
      const int q = q0 + w * 32 + mi * 16 + lane16;
      unsigned short* op = ctx + ((size_t)b * SS + q) * EE + h * DD + quad * 4;
#pragma unroll
      for (int dt = 0; dt < 8; ++dt) {
        ushort4 o;
        o.x = f2bf(acc[dt][mi][0] * inv);
        o.y = f2bf(acc[dt][mi][1] * inv);
        o.z = f2bf(acc[dt][mi][2] * inv);
        o.w = f2bf(acc[dt][mi][3] * inv);
        *(ushort4*)(op + dt * 16) = o;
      }
    }
  }
}

// ---------------------------------------------------------------------------
// Launch
// ---------------------------------------------------------------------------
extern "C" void kernel_launch(void* const* d_in, const int* in_sizes, int n_in,
                              void* d_out, int out_size, void* d_ws,
                              size_t ws_size, hipStream_t stream) {
  const float* x    = (const float*)d_in[0];
  const float* wqkv = (const float*)d_in[1];
  const float* bqkv = (const float*)d_in[2];
  const float* wout = (const float*)d_in[3];
  const float* bout = (const float*)d_in[4];
  float* out = (float*)d_out;

  unsigned short* qkvb = (unsigned short*)d_ws;      // 25165824 elems
  unsigned short* xb   = qkvb + (size_t)25165824;    //  8388608
  unsigned short* wqb  = xb + (size_t)8388608;       // 12582912
  unsigned short* ctxb = wqb + (size_t)12582912;     //  8388608
  unsigned short* wob  = ctxb + (size_t)8388608;     //  4194304
  unsigned short* vtb  = wob + (size_t)4194304;      //  8388608

  const int M = BB * SS;  // 4096

  cast_f32_bf16<<<8192, 256, 0, stream>>>(x, xb, 2097152);
  cast_f32_bf16<<<12288, 256, 0, stream>>>(wqkv, wqb, 3145728);
  cast_f32_bf16<<<4096, 256, 0, stream>>>(wout, wob, 1048576);

  {
    // 256^2 8-phase: grid (M/256)*(N/256) = 16*24 = 384 (%8==0 for swizzle)
    gemm256_8ph<unsigned short><<<dim3(384), 512, 0, stream>>>(
        xb, wqb, bqkv, qkvb, M, FF, EE);
  }
  {
    const int total = BB * SS * HH * 64;
    rotary_kernel<<<total / 256, 256, 0, stream>>>(qkvb);
  }
  {
    dim3 grid(SS / 64, DD / 64, BB * HH);
    transpose_v<<<grid, 256, 0, stream>>>(qkvb, vtb);
  }
  {
    attn_mfma<<<dim3(256), 256, 0, stream>>>(qkvb, vtb, ctxb);
  }
  {
    dim3 grid(EE / 128, M / 128);
    gemm_bf16_mfma<float><<<grid, 256, 0, stream>>>(
        ctxb, wob, bout, out, M, EE, EE);
  }
}

// Round 2
// 441.889 us; speedup vs baseline: 1.0249x; 1.0249x over previous
//
#include <hip/hip_runtime.h>
#include <math.h>

// Problem constants
#define BB 2
#define SS 2048
#define EE 2048
#define HH 16
#define DD 128
#define FF 6144   // 3*E

typedef __attribute__((ext_vector_type(8))) short short8;
typedef __attribute__((ext_vector_type(4))) float floatx4;

static __device__ __forceinline__ unsigned short f2bf(float x) {
  unsigned u = __float_as_uint(x);
  u += 0x7fffu + ((u >> 16) & 1u);
  return (unsigned short)(u >> 16);
}
static __device__ __forceinline__ float bf2f(unsigned short h) {
  return __uint_as_float((unsigned)h << 16);
}

#define GLOAD_LDS16(gp, lp)                                       \
  __builtin_amdgcn_global_load_lds(                               \
      (const __attribute__((address_space(1))) void*)(gp),        \
      (__attribute__((address_space(3))) void*)(lp), 16, 0, 0)

// ---------------------------------------------------------------------------
// fp32 -> bf16 cast (float4 in, ushort4 out)
// ---------------------------------------------------------------------------
__global__ __launch_bounds__(256) void cast_f32_bf16(
    const float* __restrict__ in, unsigned short* __restrict__ out, int n4) {
  const int i = blockIdx.x * 256 + threadIdx.x;
  if (i >= n4) return;
  const float4 v = ((const float4*)in)[i];
  ushort4 o;
  o.x = f2bf(v.x); o.y = f2bf(v.y); o.z = f2bf(v.z); o.w = f2bf(v.w);
  ((ushort4*)out)[i] = o;
}

static __device__ __forceinline__ void store_out(float* p, float v) { *p = v; }
static __device__ __forceinline__ void store_out(unsigned short* p, float v) {
  *p = f2bf(v);
}

// ---------------------------------------------------------------------------
// bf16 MFMA GEMM, double-buffered 128^2 (kept for the out-projection).
// ---------------------------------------------------------------------------
template <typename OutT>
__global__ __launch_bounds__(256) void gemm_bf16_mfma(
    const unsigned short* __restrict__ A, const unsigned short* __restrict__ Bt,
    const float* __restrict__ bias, OutT* __restrict__ C,
    int M, int N, int K) {
  __shared__ unsigned short As[2][128][32];
  __shared__ unsigned short Bs[2][128][32];
  const int tid = threadIdx.x;
  const int L = tid & 63;
  const int w = tid >> 6;
  const int m0 = blockIdx.y * 128;
  const int n0 = blockIdx.x * 128;

  const int i0 = w * 2;
  const int lrow = L >> 2;
  const int lcol = (L & 3) * 8;
  const size_t a_off0 = (size_t)(m0 + (i0 + 0) * 16 + lrow) * K + lcol;
  const size_t a_off1 = (size_t)(m0 + (i0 + 1) * 16 + lrow) * K + lcol;
  const size_t b_off0 = (size_t)(n0 + (i0 + 0) * 16 + lrow) * K + lcol;
  const size_t b_off1 = (size_t)(n0 + (i0 + 1) * 16 + lrow) * K + lcol;

  const int wr = (w >> 1) * 64;
  const int wc = (w & 1) * 64;
  const int lane16 = L & 15;
  const int quad = L >> 4;

  floatx4 acc[4][4] = {};

  GLOAD_LDS16(A + a_off0, &As[0][(i0 + 0) * 16][0]);
  GLOAD_LDS16(A + a_off1, &As[0][(i0 + 1) * 16][0]);
  GLOAD_LDS16(Bt + b_off0, &Bs[0][(i0 + 0) * 16][0]);
  GLOAD_LDS16(Bt + b_off1, &Bs[0][(i0 + 1) * 16][0]);

  for (int k0 = 0; k0 < K; k0 += 32) {
    const int cur = (k0 >> 5) & 1;
    __syncthreads();
    if (k0 + 32 < K) {
      const int nxt = cur ^ 1;
      GLOAD_LDS16(A + a_off0 + k0 + 32, &As[nxt][(i0 + 0) * 16][0]);
      GLOAD_LDS16(A + a_off1 + k0 + 32, &As[nxt][(i0 + 1) * 16][0]);
      GLOAD_LDS16(Bt + b_off0 + k0 + 32, &Bs[nxt][(i0 + 0) * 16][0]);
      GLOAD_LDS16(Bt + b_off1 + k0 + 32, &Bs[nxt][(i0 + 1) * 16][0]);
    }

    short8 a[4], b[4];
#pragma unroll
    for (int mi = 0; mi < 4; ++mi)
      a[mi] = *(const short8*)(&As[cur][wr + mi * 16 + lane16][quad * 8]);
#pragma unroll
    for (int ni = 0; ni < 4; ++ni)
      b[ni] = *(const short8*)(&Bs[cur][wc + ni * 16 + lane16][quad * 8]);
#pragma unroll
    for (int mi = 0; mi < 4; ++mi)
#pragma unroll
      for (int ni = 0; ni < 4; ++ni)
        acc[mi][ni] = __builtin_amdgcn_mfma_f32_16x16x32_bf16(
            a[mi], b[ni], acc[mi][ni], 0, 0, 0);
  }

#pragma unroll
  for (int ni = 0; ni < 4; ++ni) {
    const int col = n0 + wc + ni * 16 + lane16;
    const float bv = bias[col];
#pragma unroll
    for (int mi = 0; mi < 4; ++mi) {
      const int row = m0 + wr + mi * 16 + quad * 4;
#pragma unroll
      for (int r = 0; r < 4; ++r)
        store_out(&C[(size_t)(row + r) * N + col], acc[mi][ni][r] + bv);
    }
  }
}

// ---------------------------------------------------------------------------
// 256x256 8-phase bf16 GEMM.
// This round: (a) column-major XCD chunks (each XCD owns 3 B-panel columns ->
// B L2-resident; A streams from shared L3), (b) DISTANCE-2 prefetch: tile t
// stages tile t+2 into the CURRENT buffer c, each region right after its last
// read this tile (A01+B01 at P1, B23 at P2, A23 at P3) -> uniform 6-phase
// (~1200 cy) slack per load, covering HBM-miss latency. Counted waits:
//   P0-end vmcnt(10), P1-end vmcnt(12), P2-end none, P3-end vmcnt(12)
// (derived from issue order [P1:4][P2:2][P3:2] per tile; never drained to 0).
// Last-2-tile stages read <=2 K-tiles OOB (still inside workspace) and write
// dead LDS regions under the same write-after-read invariant -> no guards.
// ---------------------------------------------------------------------------
template <typename OutT>
__global__ __launch_bounds__(512, 2) void gemm256_8ph(
    const unsigned short* __restrict__ A, const unsigned short* __restrict__ Bt,
    const float* __restrict__ bias, OutT* __restrict__ C,
    int M, int N, int K) {
  __shared__ __align__(16) unsigned short As[2][16384];
  __shared__ __align__(16) unsigned short Bs[2][16384];

  const int tid = threadIdx.x;
  const int w = tid >> 6;
  const int L = tid & 63;
  const int lane16 = L & 15;
  const int quad = L >> 4;
  const int wm = w >> 2;   // 0..1
  const int wn = w & 3;    // 0..3

  // XCD-aware bijective swizzle, column-major within each XCD chunk:
  // chunk k = wg in [k*q8,(k+1)*q8) covers q8/nby B-columns x all M-rows.
  const int nby = M >> 8;
  const int q8 = gridDim.x >> 3;
  const int wg = (blockIdx.x & 7) * q8 + (blockIdx.x >> 3);
  const int by = wg % nby;
  const int bx = wg / nby;
  const int m0 = by << 8;
  const int n0 = bx << 8;

  // ---- staging source offsets (pre-swizzled global, rule #21) ----
  const int lA = ((w >> 1) << 4) + (L >> 2);
  const int scol = ((w & 1) << 5) + (((L & 3) * 8) ^ ((L & 32) ? 16 : 0));
  unsigned aoff[4], boff[4];
#pragma unroll
  for (int j = 0; j < 4; ++j) {
    const int ra = ((j & 1) << 7) | ((j >> 1) << 6) | lA;
    aoff[j] = (unsigned)(m0 + ra) * (unsigned)K + scol;
    const int lB = j * 64 + lA;
    const int rB = (((lB >> 5) & 3) << 6) | (((lB >> 7) & 1) << 5) | (lB & 31);
    boff[j] = (unsigned)(n0 + rB) * (unsigned)K + scol;
  }
  const int ldst = w * 512;

  // ---- ds_read addressing (st_16x32 swizzle) ----
  const int sq = (quad * 8) ^ ((lane16 & 8) << 1);
  const int rbase = lane16 * 32 + sq;

  floatx4 acc[8][4] = {};

  // prologue: tile0 -> buf0, tile1 -> buf1, group order = in-loop order
  GLOAD_LDS16(A + aoff[0], &As[0][0 * 4096 + ldst]);
  GLOAD_LDS16(A + aoff[1], &As[0][1 * 4096 + ldst]);
  GLOAD_LDS16(Bt + boff[0], &Bs[0][0 * 4096 + ldst]);
  GLOAD_LDS16(Bt + boff[1], &Bs[0][1 * 4096 + ldst]);
  GLOAD_LDS16(Bt + boff[2], &Bs[0][2 * 4096 + ldst]);
  GLOAD_LDS16(Bt + boff[3], &Bs[0][3 * 4096 + ldst]);
  GLOAD_LDS16(A + aoff[2], &As[0][2 * 4096 + ldst]);
  GLOAD_LDS16(A + aoff[3], &As[0][3 * 4096 + ldst]);
  GLOAD_LDS16(A + aoff[0] + 64, &As[1][0 * 4096 + ldst]);
  GLOAD_LDS16(A + aoff[1] + 64, &As[1][1 * 4096 + ldst]);
  GLOAD_LDS16(Bt + boff[0] + 64, &Bs[1][0 * 4096 + ldst]);
  GLOAD_LDS16(Bt + boff[1] + 64, &Bs[1][1 * 4096 + ldst]);
  GLOAD_LDS16(Bt + boff[2] + 64, &Bs[1][2 * 4096 + ldst]);
  GLOAD_LDS16(Bt + boff[3] + 64, &Bs[1][3 * 4096 + ldst]);
  GLOAD_LDS16(A + aoff[2] + 64, &As[1][2 * 4096 + ldst]);
  GLOAD_LDS16(A + aoff[3] + 64, &As[1][3 * 4096 + ldst]);
  asm volatile("s_waitcnt vmcnt(8)" ::: "memory");
  __builtin_amdgcn_s_barrier();

  const int NT = K >> 6;
  short8 a[4][2], b0[2][2], b1[2][2];

  for (int t = 0; t < NT; ++t) {
    const int c = t & 1;
    const unsigned kn2 = (unsigned)(t + 2) << 6;
    const unsigned short* Ac = &As[c][0];
    const unsigned short* Bc = &Bs[c][0];

    // ---------------- P0: read A0(8)+B0(4); mfma (A0,B0)
#pragma unroll
    for (int i = 0; i < 4; ++i)
#pragma unroll
      for (int kk = 0; kk < 2; ++kk)
        a[i][kk] = *(const short8*)(Ac + ((wm * 4 + i) * 2 + kk) * 512 + rbase);
#pragma unroll
    for (int j = 0; j < 2; ++j)
#pragma unroll
      for (int kk = 0; kk < 2; ++kk)
        b0[j][kk] = *(const short8*)(Bc + ((wn * 2 + j) * 2 + kk) * 512 + rbase);
    asm volatile("s_waitcnt lgkmcnt(8)" ::: "memory");
    __builtin_amdgcn_s_barrier();
    asm volatile("s_waitcnt lgkmcnt(0)" ::: "memory");
    __builtin_amdgcn_s_setprio(1);
#pragma unroll
    for (int i = 0; i < 4; ++i)
#pragma unroll
      for (int j = 0; j < 2; ++j)
#pragma unroll
        for (int kk = 0; kk < 2; ++kk)
          acc[i][j] = __builtin_amdgcn_mfma_f32_16x16x32_bf16(
              a[i][kk], b0[j][kk], acc[i][j], 0, 0, 0);
    __builtin_amdgcn_s_setprio(0);
    asm volatile("s_waitcnt vmcnt(10)" ::: "memory");
    __builtin_amdgcn_s_barrier();

    // ---------------- P1: read B1(4); stage A01+B01 (t+2 -> buf c); mfma (A0,B1)
#pragma unroll
    for (int j = 0; j < 2; ++j)
#pragma unroll
      for (int kk = 0; kk < 2; ++kk)
        b1[j][kk] =
            *(const short8*)(Bc + ((8 + wn * 2 + j) * 2 + kk) * 512 + rbase);
    GLOAD_LDS16(A + aoff[0] + kn2, &As[c][0 * 4096 + ldst]);
    GLOAD_LDS16(A + aoff[1] + kn2, &As[c][1 * 4096 + ldst]);
    GLOAD_LDS16(Bt + boff[0] + kn2, &Bs[c][0 * 4096 + ldst]);
    GLOAD_LDS16(Bt + boff[1] + kn2, &Bs[c][1 * 4096 + ldst]);
    __builtin_amdgcn_s_barrier();
    asm volatile("s_waitcnt lgkmcnt(0)" ::: "memory");
    __builtin_amdgcn_s_setprio(1);
#pragma unroll
    for (int i = 0; i < 4; ++i)
#pragma unroll
      for (int j = 0; j < 2; ++j)
#pragma unroll
        for (int kk = 0; kk < 2; ++kk)
          acc[i][2 + j] = __builtin_amdgcn_mfma_f32_16x16x32_bf16(
              a[i][kk], b1[j][kk], acc[i][2 + j], 0, 0, 0);
    __builtin_amdgcn_s_setprio(0);
    asm volatile("s_waitcnt vmcnt(12)" ::: "memory");
    __builtin_amdgcn_s_barrier();

    // ---------------- P2: read A1(8); stage B23; mfma (A1,B1)
#pragma unroll
    for (int i = 0; i < 4; ++i)
#pragma unroll
      for (int kk = 0; kk < 2; ++kk)
        a[i][kk] =
            *(const short8*)(Ac + ((8 + wm * 4 + i) * 2 + kk) * 512 + rbase);
    GLOAD_LDS16(Bt + boff[2] + kn2, &Bs[c][2 * 4096 + ldst]);
    GLOAD_LDS16(Bt + boff[3] + kn2, &Bs[c][3 * 4096 + ldst]);
    __builtin_amdgcn_s_barrier();
    asm volatile("s_waitcnt lgkmcnt(0)" ::: "memory");
    __builtin_amdgcn_s_setprio(1);
#pragma unroll
    for (int i = 0; i < 4; ++i)
#pragma unroll
      for (int j = 0; j < 2; ++j)
#pragma unroll
        for (int kk = 0; kk < 2; ++kk)
          acc[4 + i][2 + j] = __builtin_amdgcn_mfma_f32_16x16x32_bf16(
              a[i][kk], b1[j][kk], acc[4 + i][2 + j], 0, 0, 0);
    __builtin_amdgcn_s_setprio(0);
    __builtin_amdgcn_s_barrier();

    // ---------------- P3: no reads; stage A23; mfma (A1,B0)
    GLOAD_LDS16(A + aoff[2] + kn2, &As[c][2 * 4096 + ldst]);
    GLOAD_LDS16(A + aoff[3] + kn2, &As[c][3 * 4096 + ldst]);
    __builtin_amdgcn_s_barrier();
    __builtin_amdgcn_s_setprio(1);
#pragma unroll
    for (int i = 0; i < 4; ++i)
#pragma unroll
      for (int j = 0; j < 2; ++j)
#pragma unroll
        for (int kk = 0; kk < 2; ++kk)
          acc[4 + i][j] = __builtin_amdgcn_mfma_f32_16x16x32_bf16(
              a[i][kk], b0[j][kk], acc[4 + i][j], 0, 0, 0);
    __builtin_amdgcn_s_setprio(0);
    asm volatile("s_waitcnt vmcnt(12)" ::: "memory");
    __builtin_amdgcn_s_barrier();
  }

  // epilogue
#pragma unroll
  for (int ni = 0; ni < 4; ++ni) {
    const int col = n0 + wn * 64 + ni * 16 + lane16;
    const float bv = bias[col];
#pragma unroll
    for (int mi = 0; mi < 8; ++mi) {
      const int row = m0 + wm * 128 + mi * 16 + quad * 4;
#pragma unroll
      for (int r = 0; r < 4; ++r)
        store_out(&C[(size_t)(row + r) * N + col], acc[mi][ni][r] + bv);
    }
  }
}

// ---------------------------------------------------------------------------
// Rotary on bf16 qkv in place. qkv layout [B][S][3][H][D] bf16.
// ---------------------------------------------------------------------------
__global__ __launch_bounds__(256) void rotary_kernel(unsigned short* __restrict__ qkv) {
  const int idx = blockIdx.x * blockDim.x + threadIdx.x;
  const int d = idx & 63;
  const int h = (idx >> 6) & (HH - 1);
  const int s = (idx >> 10) & (SS - 1);
  const int b = idx >> 21;

  // inv_freq = 10000^(-d/64) = exp(-d * ln(10000)/64)
  const float inv_freq = __expf(-(float)d * 0.14391156509f);
  float sn, c;
  __sincosf((float)s * inv_freq, &sn, &c);

  const size_t base = ((size_t)b * SS + s) * FF + h * DD + d;
  unsigned short* q = qkv + base;
  unsigned short* k = qkv + base + EE;

  const float q1 = bf2f(q[0]), q2 = bf2f(q[64]);
  q[0]  = f2bf(q1 * c - q2 * sn);
  q[64] = f2bf(q2 * c + q1 * sn);
  const float k1 = bf2f(k[0]), k2 = bf2f(k[64]);
  k[0]  = f2bf(k1 * c - k2 * sn);
  k[64] = f2bf(k2 * c + k1 * sn);
}

// ---------------------------------------------------------------------------
// V transpose: qkv V slab [b][s][h][d] -> vt [b*H+h][d][s]   (bf16)
// ---------------------------------------------------------------------------
__global__ __launch_bounds__(256) void transpose_v(
    const unsigned short* __restrict__ qkv, unsigned short* __restrict__ vt) {
  __shared__ unsigned short T[64][72];
  const int t = threadIdx.x;
  const int s0 = blockIdx.x * 64;
  const int d0 = blockIdx.y * 64;
  const int bh = blockIdx.z;
  const int b = bh >> 4, h = bh & 15;
  {
    const int r = t >> 2, c = (t & 3) * 16;
    const unsigned short* src =
        qkv + ((size_t)b * SS + s0 + r) * FF + 2 * EE + h * DD + d0 + c;
    const uint4 u0 = *(const uint4*)src;
    const uint4 u1 = *(const uint4*)(src + 8);
    *(uint4*)&T[r][c] = u0;
    *(uint4*)&T[r][c + 8] = u1;
  }
  __syncthreads();
  {
    const int rr = t >> 2, cc = (t & 3) * 16;
    unsigned short vals[16];
#pragma unroll
    for (int j = 0; j < 16; ++j) vals[j] = T[cc + j][rr];
    unsigned short* dst =
        vt + (size_t)bh * DD * SS + (size_t)(d0 + rr) * SS + s0 + cc;
    *(uint4*)dst = *(uint4*)&vals[0];
    *(uint4*)(dst + 8) = *(uint4*)&vals[8];
  }
}

// ---------------------------------------------------------------------------
// MFMA flash attention, causal (unchanged).
// ---------------------------------------------------------------------------
#define ATQ 128
#define ATK 32
#define SPAD 40
#define NQT (SS / ATQ)

__global__ __launch_bounds__(256, 2) void attn_mfma(
    const unsigned short* __restrict__ qkv,
    const unsigned short* __restrict__ vt,
    unsigned short* __restrict__ ctx) {
  __shared__ __align__(16) unsigned short Ksh[2][ATK * DD];
  __shared__ __align__(16) unsigned short Vsh[2][DD * ATK];
  __shared__ __align__(16) unsigned short Ssh[ATQ][SPAD];

  const int tid = threadIdx.x;
  const int L = tid & 63;
  const int w = tid >> 6;
  const int lane16 = L & 15;
  const int quad = L >> 4;

  const int flat = blockIdx.x;
  const int pi = flat >> 5;
  const int bh_lin = flat & 31;
  const int b = bh_lin >> 4;
  const int h = bh_lin & 15;
  const int bh = b * HH + h;
  const float scale = 0.08838834764831845f;

  size_t koff[2], voff[2];
  int kdst[2], vdst[2];
#pragma unroll
  for (int j = 0; j < 2; ++j) {
    const int ck = j * 256 + tid;
    const int kk = ck >> 4;
    const int cgk = (ck & 15) ^ (kk & 15);
    koff[j] = ((size_t)b * SS + kk) * FF + EE + h * DD + cgk * 8;
    kdst[j] = (j * 256 + w * 64) * 8;
    const int d = ck >> 2;
    const int cgv = (ck & 3) ^ (d & 3);
    voff[j] = (size_t)bh * DD * SS + (size_t)d * SS + cgv * 8;
    vdst[j] = kdst[j];
  }

#pragma unroll 1
  for (int phase = 0; phase < 2; ++phase) {
    const int qb = phase ? pi : (NQT - 1 - pi);
    const int q0 = qb * ATQ;

    short8 qf[2][4];
#pragma unroll
    for (int mi = 0; mi < 2; ++mi) {
      const int q = q0 + w * 32 + mi * 16 + lane16;
      const unsigned short* qp =
          qkv + ((size_t)b * SS + q) * FF + h * DD + quad * 8;
#pragma unroll
      for (int dc = 0; dc < 4; ++dc)
        qf[mi][dc] = *(const short8*)(qp + dc * 32);
    }

    floatx4 acc[8][2] = {};
    float m_i[2] = {-3.0e38f, -3.0e38f};
    float l_i[2] = {0.0f, 0.0f};

    const int nkt = 4 * qb + 4;
    const int mykt = 4 * qb + w;

#pragma unroll
    for (int j = 0; j < 2; ++j) {
      GLOAD_LDS16(qkv + koff[j], &Ksh[0][kdst[j]]);
      GLOAD_LDS16(vt + voff[j], &Vsh[0][vdst[j]]);
    }

    for (int kt = 0; kt < nkt; ++kt) {
      const int cur = kt & 1;
      __syncthreads();
      if (kt + 1 < nkt) {
        const size_t ka = (size_t)(kt + 1) * ATK * FF;
        const int va = (kt + 1) * ATK;
#pragma unroll
        for (int j = 0; j < 2; ++j) {
          GLOAD_LDS16(qkv + koff[j] + ka, &Ksh[cur ^ 1][kdst[j]]);
          GLOAD_LDS16(vt + voff[j] + va, &Vsh[cur ^ 1][vdst[j]]);
        }
      }
      if (kt > mykt) continue;
      const int k0 = kt * ATK;
      const unsigned short* Kc = Ksh[cur];
      const unsigned short* Vc = Vsh[cur];

      floatx4 st[2][2] = {};
#pragma unroll
      for (int kkt = 0; kkt < 2; ++kkt) {
        const unsigned short* krow = Kc + (kkt * 16 + lane16) * 128;
#pragma unroll
        for (int dc = 0; dc < 4; ++dc) {
          const short8 kf =
              *(const short8*)(krow + ((dc * 4 + quad) ^ lane16) * 8);
#pragma unroll
          for (int mi = 0; mi < 2; ++mi)
            st[kkt][mi] = __builtin_amdgcn_mfma_f32_16x16x32_bf16(
                kf, qf[mi][dc], st[kkt][mi], 0, 0, 0);
        }
      }

      const bool needmask = (kt == mykt);
#pragma unroll
      for (int mi = 0; mi < 2; ++mi) {
        const int q_glob = q0 + w * 32 + mi * 16 + lane16;
#pragma unroll
        for (int kkt = 0; kkt < 2; ++kkt) {
          const int kkb = k0 + kkt * 16 + quad * 4;
#pragma unroll
          for (int r = 0; r < 4; ++r) {
            float v = st[kkt][mi][r] * scale;
            if (needmask && (kkb + r) > q_glob) v = -3.0e38f;
            st[kkt][mi][r] = v;
          }
        }
      }

      float alpha[2];
#pragma unroll
      for (int mi = 0; mi < 2; ++mi) {
        float tm = -3.0e38f;
#pragma unroll
        for (int kkt = 0; kkt < 2; ++kkt)
#pragma unroll
          for (int r = 0; r < 4; ++r) tm = fmaxf(tm, st[kkt][mi][r]);
        tm = fmaxf(tm, __shfl_xor(tm, 16));
        tm = fmaxf(tm, __shfl_xor(tm, 32));
        const float mn = fmaxf(m_i[mi], tm);
        alpha[mi] = __expf(m_i[mi] - mn);
        m_i[mi] = mn;

        float rs = 0.0f;
#pragma unroll
        for (int kkt = 0; kkt < 2; ++kkt)
#pragma unroll
          for (int r = 0; r < 4; ++r) {
            const float p = __expf(st[kkt][mi][r] - mn);
            st[kkt][mi][r] = p;
            rs += p;
          }
        rs += __shfl_xor(rs, 16);
        rs += __shfl_xor(rs, 32);
        l_i[mi] = l_i[mi] * alpha[mi] + rs;

#pragma unroll
        for (int kkt = 0; kkt < 2; ++kkt) {
          ushort4 pk;
          pk.x = f2bf(st[kkt][mi][0]);
          pk.y = f2bf(st[kkt][mi][1]);
          pk.z = f2bf(st[kkt][mi][2]);
          pk.w = f2bf(st[kkt][mi][3]);
          *(ushort4*)(&Ssh[w * 32 + mi * 16 + lane16][kkt * 16 + quad * 4]) =
              pk;
        }
      }

#pragma unroll
      for (int dt = 0; dt < 8; ++dt)
#pragma unroll
        for (int mi = 0; mi < 2; ++mi)
#pragma unroll
          for (int r = 0; r < 4; ++r) acc[dt][mi][r] *= alpha[mi];

      short8 pa[2];
#pragma unroll
      for (int mi = 0; mi < 2; ++mi)
        pa[mi] = *(const short8*)(&Ssh[w * 32 + mi * 16 + lane16][quad * 8]);
      const int vpos = (quad ^ (lane16 & 3)) * 8;
#pragma unroll
      for (int dt = 0; dt < 8; ++dt) {
        const short8 vf =
            *(const short8*)(Vc + (dt * 16 + lane16) * 32 + vpos);
#pragma unroll
        for (int mi = 0; mi < 2; ++mi)
          acc[dt][mi] = __builtin_amdgcn_mfma_f32_16x16x32_bf16(
              vf, pa[mi], acc[dt][mi], 0, 0, 0);
      }
    }

#pragma unroll
    for (int mi = 0; mi < 2; ++mi) {
      const float inv = 1.0f / l_i[mi];
      const int q = q0 + w * 32 + mi * 16 + lane16;
      unsigned short* op = ctx + ((size_t)b * SS + q) * EE + h * DD + quad * 4;
#pragma unroll
      for (int dt = 0; dt < 8; ++dt) {
        ushort4 o;
        o.x = f2bf(acc[dt][mi][0] * inv);
        o.y = f2bf(acc[dt][mi][1] * inv);
        o.z = f2bf(acc[dt][mi][2] * inv);
        o.w = f2bf(acc[dt][mi][3] * inv);
        *(ushort4*)(op + dt * 16) = o;
      }
    }
  }
}

// ---------------------------------------------------------------------------
// Launch
// ---------------------------------------------------------------------------
extern "C" void kernel_launch(void* const* d_in, const int* in_sizes, int n_in,
                              void* d_out, int out_size, void* d_ws,
                              size_t ws_size, hipStream_t stream) {
  const float* x    = (const float*)d_in[0];
  const float* wqkv = (const float*)d_in[1];
  const float* bqkv = (const float*)d_in[2];
  const float* wout = (const float*)d_in[3];
  const float* bout = (const float*)d_in[4];
  float* out = (float*)d_out;

  unsigned short* qkvb = (unsigned short*)d_ws;      // 25165824 elems
  unsigned short* xb   = qkvb + (size_t)25165824;    //  8388608
  unsigned short* wqb  = xb + (size_t)8388608;       // 12582912
  unsigned short* ctxb = wqb + (size_t)12582912;     //  8388608
  unsigned short* wob  = ctxb + (size_t)8388608;     //  4194304
  unsigned short* vtb  = wob + (size_t)4194304;      //  8388608

  const int M = BB * SS;  // 4096

  cast_f32_bf16<<<8192, 256, 0, stream>>>(x, xb, 2097152);
  cast_f32_bf16<<<12288, 256, 0, stream>>>(wqkv, wqb, 3145728);
  cast_f32_bf16<<<4096, 256, 0, stream>>>(wout, wob, 1048576);

  {
    // 256^2 8-phase: grid 16*24 = 384 (%8==0 for XCD swizzle)
    gemm256_8ph<unsigned short><<<dim3(384), 512, 0, stream>>>(
        xb, wqb, bqkv, qkvb, M, FF, EE);
  }
  {
    const int total = BB * SS * HH * 64;
    rotary_kernel<<<total / 256, 256, 0, stream>>>(qkvb);
  }
  {
    dim3 grid(SS / 64, DD / 64, BB * HH);
    transpose_v<<<grid, 256, 0, stream>>>(qkvb, vtb);
  }
  {
    attn_mfma<<<dim3(256), 256, 0, stream>>>(qkvb, vtb, ctxb);
  }
  {
    dim3 grid(EE / 128, M / 128);
    gemm_bf16_mfma<float><<<grid, 256, 0, stream>>>(
        ctxb, wob, bout, out, M, EE, EE);
  }
}

// Round 3
// 438.201 us; speedup vs baseline: 1.0335x; 1.0084x over previous
//
#include <hip/hip_runtime.h>
#include <math.h>

// Problem constants
#define BB 2
#define SS 2048
#define EE 2048
#define HH 16
#define DD 128
#define FF 6144   // 3*E

typedef __attribute__((ext_vector_type(8))) short short8;
typedef __attribute__((ext_vector_type(4))) float floatx4;

static __device__ __forceinline__ unsigned short f2bf(float x) {
  unsigned u = __float_as_uint(x);
  u += 0x7fffu + ((u >> 16) & 1u);
  return (unsigned short)(u >> 16);
}
static __device__ __forceinline__ float bf2f(unsigned short h) {
  return __uint_as_float((unsigned)h << 16);
}

#define GLOAD_LDS16(gp, lp)                                       \
  __builtin_amdgcn_global_load_lds(                               \
      (const __attribute__((address_space(1))) void*)(gp),        \
      (__attribute__((address_space(3))) void*)(lp), 16, 0, 0)

// ---------------------------------------------------------------------------
// fp32 -> bf16 cast (float4 in, ushort4 out)
// ---------------------------------------------------------------------------
__global__ __launch_bounds__(256) void cast_f32_bf16(
    const float* __restrict__ in, unsigned short* __restrict__ out, int n4) {
  const int i = blockIdx.x * 256 + threadIdx.x;
  if (i >= n4) return;
  const float4 v = ((const float4*)in)[i];
  ushort4 o;
  o.x = f2bf(v.x); o.y = f2bf(v.y); o.z = f2bf(v.z); o.w = f2bf(v.w);
  ((ushort4*)out)[i] = o;
}

static __device__ __forceinline__ void store_out(float* p, float v) { *p = v; }
static __device__ __forceinline__ void store_out(unsigned short* p, float v) {
  *p = f2bf(v);
}

// ---------------------------------------------------------------------------
// bf16 MFMA GEMM, double-buffered 128^2 (kept for the out-projection).
// ---------------------------------------------------------------------------
template <typename OutT>
__global__ __launch_bounds__(256) void gemm_bf16_mfma(
    const unsigned short* __restrict__ A, const unsigned short* __restrict__ Bt,
    const float* __restrict__ bias, OutT* __restrict__ C,
    int M, int N, int K) {
  __shared__ unsigned short As[2][128][32];
  __shared__ unsigned short Bs[2][128][32];
  const int tid = threadIdx.x;
  const int L = tid & 63;
  const int w = tid >> 6;
  const int m0 = blockIdx.y * 128;
  const int n0 = blockIdx.x * 128;

  const int i0 = w * 2;
  const int lrow = L >> 2;
  const int lcol = (L & 3) * 8;
  const size_t a_off0 = (size_t)(m0 + (i0 + 0) * 16 + lrow) * K + lcol;
  const size_t a_off1 = (size_t)(m0 + (i0 + 1) * 16 + lrow) * K + lcol;
  const size_t b_off0 = (size_t)(n0 + (i0 + 0) * 16 + lrow) * K + lcol;
  const size_t b_off1 = (size_t)(n0 + (i0 + 1) * 16 + lrow) * K + lcol;

  const int wr = (w >> 1) * 64;
  const int wc = (w & 1) * 64;
  const int lane16 = L & 15;
  const int quad = L >> 4;

  floatx4 acc[4][4] = {};

  GLOAD_LDS16(A + a_off0, &As[0][(i0 + 0) * 16][0]);
  GLOAD_LDS16(A + a_off1, &As[0][(i0 + 1) * 16][0]);
  GLOAD_LDS16(Bt + b_off0, &Bs[0][(i0 + 0) * 16][0]);
  GLOAD_LDS16(Bt + b_off1, &Bs[0][(i0 + 1) * 16][0]);

  for (int k0 = 0; k0 < K; k0 += 32) {
    const int cur = (k0 >> 5) & 1;
    __syncthreads();
    if (k0 + 32 < K) {
      const int nxt = cur ^ 1;
      GLOAD_LDS16(A + a_off0 + k0 + 32, &As[nxt][(i0 + 0) * 16][0]);
      GLOAD_LDS16(A + a_off1 + k0 + 32, &As[nxt][(i0 + 1) * 16][0]);
      GLOAD_LDS16(Bt + b_off0 + k0 + 32, &Bs[nxt][(i0 + 0) * 16][0]);
      GLOAD_LDS16(Bt + b_off1 + k0 + 32, &Bs[nxt][(i0 + 1) * 16][0]);
    }

    short8 a[4], b[4];
#pragma unroll
    for (int mi = 0; mi < 4; ++mi)
      a[mi] = *(const short8*)(&As[cur][wr + mi * 16 + lane16][quad * 8]);
#pragma unroll
    for (int ni = 0; ni < 4; ++ni)
      b[ni] = *(const short8*)(&Bs[cur][wc + ni * 16 + lane16][quad * 8]);
#pragma unroll
    for (int mi = 0; mi < 4; ++mi)
#pragma unroll
      for (int ni = 0; ni < 4; ++ni)
        acc[mi][ni] = __builtin_amdgcn_mfma_f32_16x16x32_bf16(
            a[mi], b[ni], acc[mi][ni], 0, 0, 0);
  }

#pragma unroll
  for (int ni = 0; ni < 4; ++ni) {
    const int col = n0 + wc + ni * 16 + lane16;
    const float bv = bias[col];
#pragma unroll
    for (int mi = 0; mi < 4; ++mi) {
      const int row = m0 + wr + mi * 16 + quad * 4;
#pragma unroll
      for (int r = 0; r < 4; ++r)
        store_out(&C[(size_t)(row + r) * N + col], acc[mi][ni][r] + bv);
    }
  }
}

// ---------------------------------------------------------------------------
// 256x256 8-phase bf16 GEMM, RELAXED phases.
// This round: single barrier per phase (4/tile, was 8). Per phase:
//   [ds_reads ; stage-issue ; MFMA(compiler fine-grained lgkmcnt) ;
//    sched_barrier(0) ; s_barrier]
// -> LDS reads overlap MFMA within-wave (per-operand lgkmcnt) and across
// waves (late readers overlap early MFMA). One counted vmcnt(8) per tile at
// P3-end: with distance-2 staging, tile t only reads data staged at t-2, and
// vmcnt(8) leaves exactly tile t's 8 DMAs in flight => everything older has
// landed before tile t+1 starts (7-8 phase slack, never drained to 0).
// Write-after-read safety needs only the one barrier per phase: every stage
// targets windows read in an EARLIER phase, and sched_barrier(0) pins reads/
// MFMA/stage inside their phase (raw s_barrier is not a compiler fence).
// ---------------------------------------------------------------------------
template <typename OutT>
__global__ __launch_bounds__(512, 2) void gemm256_8ph(
    const unsigned short* __restrict__ A, const unsigned short* __restrict__ Bt,
    const float* __restrict__ bias, OutT* __restrict__ C,
    int M, int N, int K) {
  __shared__ __align__(16) unsigned short As[2][16384];
  __shared__ __align__(16) unsigned short Bs[2][16384];

  const int tid = threadIdx.x;
  const int w = tid >> 6;
  const int L = tid & 63;
  const int lane16 = L & 15;
  const int quad = L >> 4;
  const int wm = w >> 2;   // 0..1
  const int wn = w & 3;    // 0..3

  // XCD-aware bijective swizzle, column-major within each XCD chunk.
  const int nby = M >> 8;
  const int q8 = gridDim.x >> 3;
  const int wg = (blockIdx.x & 7) * q8 + (blockIdx.x >> 3);
  const int by = wg % nby;
  const int bx = wg / nby;
  const int m0 = by << 8;
  const int n0 = bx << 8;

  // ---- staging source offsets (pre-swizzled global, rule #21) ----
  const int lA = ((w >> 1) << 4) + (L >> 2);
  const int scol = ((w & 1) << 5) + (((L & 3) * 8) ^ ((L & 32) ? 16 : 0));
  unsigned aoff[4], boff[4];
#pragma unroll
  for (int j = 0; j < 4; ++j) {
    const int ra = ((j & 1) << 7) | ((j >> 1) << 6) | lA;
    aoff[j] = (unsigned)(m0 + ra) * (unsigned)K + scol;
    const int lB = j * 64 + lA;
    const int rB = (((lB >> 5) & 3) << 6) | (((lB >> 7) & 1) << 5) | (lB & 31);
    boff[j] = (unsigned)(n0 + rB) * (unsigned)K + scol;
  }
  const int ldst = w * 512;

  // ---- ds_read addressing (st_16x32 swizzle) ----
  const int sq = (quad * 8) ^ ((lane16 & 8) << 1);
  const int rbase = lane16 * 32 + sq;

  floatx4 acc[8][4] = {};

  // prologue: tile0 -> buf0, tile1 -> buf1
  GLOAD_LDS16(A + aoff[0], &As[0][0 * 4096 + ldst]);
  GLOAD_LDS16(A + aoff[1], &As[0][1 * 4096 + ldst]);
  GLOAD_LDS16(Bt + boff[0], &Bs[0][0 * 4096 + ldst]);
  GLOAD_LDS16(Bt + boff[1], &Bs[0][1 * 4096 + ldst]);
  GLOAD_LDS16(Bt + boff[2], &Bs[0][2 * 4096 + ldst]);
  GLOAD_LDS16(Bt + boff[3], &Bs[0][3 * 4096 + ldst]);
  GLOAD_LDS16(A + aoff[2], &As[0][2 * 4096 + ldst]);
  GLOAD_LDS16(A + aoff[3], &As[0][3 * 4096 + ldst]);
  GLOAD_LDS16(A + aoff[0] + 64, &As[1][0 * 4096 + ldst]);
  GLOAD_LDS16(A + aoff[1] + 64, &As[1][1 * 4096 + ldst]);
  GLOAD_LDS16(Bt + boff[0] + 64, &Bs[1][0 * 4096 + ldst]);
  GLOAD_LDS16(Bt + boff[1] + 64, &Bs[1][1 * 4096 + ldst]);
  GLOAD_LDS16(Bt + boff[2] + 64, &Bs[1][2 * 4096 + ldst]);
  GLOAD_LDS16(Bt + boff[3] + 64, &Bs[1][3 * 4096 + ldst]);
  GLOAD_LDS16(A + aoff[2] + 64, &As[1][2 * 4096 + ldst]);
  GLOAD_LDS16(A + aoff[3] + 64, &As[1][3 * 4096 + ldst]);
  asm volatile("s_waitcnt vmcnt(8)" ::: "memory");
  __builtin_amdgcn_sched_barrier(0);
  __builtin_amdgcn_s_barrier();

  const int NT = K >> 6;
  short8 a[4][2], b0[2][2], b1[2][2];

  for (int t = 0; t < NT; ++t) {
    const int c = t & 1;
    const unsigned kn2 = (unsigned)(t + 2) << 6;
    const unsigned short* Ac = &As[c][0];
    const unsigned short* Bc = &Bs[c][0];

    // ---------------- P0: reads A0(8)+B0(4); mfma (A0,B0)
#pragma unroll
    for (int i = 0; i < 4; ++i)
#pragma unroll
      for (int kk = 0; kk < 2; ++kk)
        a[i][kk] = *(const short8*)(Ac + ((wm * 4 + i) * 2 + kk) * 512 + rbase);
#pragma unroll
    for (int j = 0; j < 2; ++j)
#pragma unroll
      for (int kk = 0; kk < 2; ++kk)
        b0[j][kk] = *(const short8*)(Bc + ((wn * 2 + j) * 2 + kk) * 512 + rbase);
    __builtin_amdgcn_s_setprio(1);
#pragma unroll
    for (int i = 0; i < 4; ++i)
#pragma unroll
      for (int j = 0; j < 2; ++j)
#pragma unroll
        for (int kk = 0; kk < 2; ++kk)
          acc[i][j] = __builtin_amdgcn_mfma_f32_16x16x32_bf16(
              a[i][kk], b0[j][kk], acc[i][j], 0, 0, 0);
    __builtin_amdgcn_s_setprio(0);
    __builtin_amdgcn_sched_barrier(0);
    __builtin_amdgcn_s_barrier();

    // ---------------- P1: reads B1(4); stage A01+B01 (t+2 -> buf c); mfma (A0,B1)
#pragma unroll
    for (int j = 0; j < 2; ++j)
#pragma unroll
      for (int kk = 0; kk < 2; ++kk)
        b1[j][kk] =
            *(const short8*)(Bc + ((8 + wn * 2 + j) * 2 + kk) * 512 + rbase);
    GLOAD_LDS16(A + aoff[0] + kn2, &As[c][0 * 4096 + ldst]);
    GLOAD_LDS16(A + aoff[1] + kn2, &As[c][1 * 4096 + ldst]);
    GLOAD_LDS16(Bt + boff[0] + kn2, &Bs[c][0 * 4096 + ldst]);
    GLOAD_LDS16(Bt + boff[1] + kn2, &Bs[c][1 * 4096 + ldst]);
    __builtin_amdgcn_s_setprio(1);
#pragma unroll
    for (int i = 0; i < 4; ++i)
#pragma unroll
      for (int j = 0; j < 2; ++j)
#pragma unroll
        for (int kk = 0; kk < 2; ++kk)
          acc[i][2 + j] = __builtin_amdgcn_mfma_f32_16x16x32_bf16(
              a[i][kk], b1[j][kk], acc[i][2 + j], 0, 0, 0);
    __builtin_amdgcn_s_setprio(0);
    __builtin_amdgcn_sched_barrier(0);
    __builtin_amdgcn_s_barrier();

    // ---------------- P2: reads A1(8); stage B23; mfma (A1,B1)
#pragma unroll
    for (int i = 0; i < 4; ++i)
#pragma unroll
      for (int kk = 0; kk < 2; ++kk)
        a[i][kk] =
            *(const short8*)(Ac + ((8 + wm * 4 + i) * 2 + kk) * 512 + rbase);
    GLOAD_LDS16(Bt + boff[2] + kn2, &Bs[c][2 * 4096 + ldst]);
    GLOAD_LDS16(Bt + boff[3] + kn2, &Bs[c][3 * 4096 + ldst]);
    __builtin_amdgcn_s_setprio(1);
#pragma unroll
    for (int i = 0; i < 4; ++i)
#pragma unroll
      for (int j = 0; j < 2; ++j)
#pragma unroll
        for (int kk = 0; kk < 2; ++kk)
          acc[4 + i][2 + j] = __builtin_amdgcn_mfma_f32_16x16x32_bf16(
              a[i][kk], b1[j][kk], acc[4 + i][2 + j], 0, 0, 0);
    __builtin_amdgcn_s_setprio(0);
    __builtin_amdgcn_sched_barrier(0);
    __builtin_amdgcn_s_barrier();

    // ---------------- P3: stage A23; mfma (A1,B0); vmcnt(8)
    GLOAD_LDS16(A + aoff[2] + kn2, &As[c][2 * 4096 + ldst]);
    GLOAD_LDS16(A + aoff[3] + kn2, &As[c][3 * 4096 + ldst]);
    __builtin_amdgcn_s_setprio(1);
#pragma unroll
    for (int i = 0; i < 4; ++i)
#pragma unroll
      for (int j = 0; j < 2; ++j)
#pragma unroll
        for (int kk = 0; kk < 2; ++kk)
          acc[4 + i][j] = __builtin_amdgcn_mfma_f32_16x16x32_bf16(
              a[i][kk], b0[j][kk], acc[4 + i][j], 0, 0, 0);
    __builtin_amdgcn_s_setprio(0);
    asm volatile("s_waitcnt vmcnt(8)" ::: "memory");
    __builtin_amdgcn_sched_barrier(0);
    __builtin_amdgcn_s_barrier();
  }

  // epilogue
#pragma unroll
  for (int ni = 0; ni < 4; ++ni) {
    const int col = n0 + wn * 64 + ni * 16 + lane16;
    const float bv = bias[col];
#pragma unroll
    for (int mi = 0; mi < 8; ++mi) {
      const int row = m0 + wm * 128 + mi * 16 + quad * 4;
#pragma unroll
      for (int r = 0; r < 4; ++r)
        store_out(&C[(size_t)(row + r) * N + col], acc[mi][ni][r] + bv);
    }
  }
}

// ---------------------------------------------------------------------------
// Rotary on bf16 qkv in place. qkv layout [B][S][3][H][D] bf16.
// ---------------------------------------------------------------------------
__global__ __launch_bounds__(256) void rotary_kernel(unsigned short* __restrict__ qkv) {
  const int idx = blockIdx.x * blockDim.x + threadIdx.x;
  const int d = idx & 63;
  const int h = (idx >> 6) & (HH - 1);
  const int s = (idx >> 10) & (SS - 1);
  const int b = idx >> 21;

  const float inv_freq = __expf(-(float)d * 0.14391156509f);
  float sn, c;
  __sincosf((float)s * inv_freq, &sn, &c);

  const size_t base = ((size_t)b * SS + s) * FF + h * DD + d;
  unsigned short* q = qkv + base;
  unsigned short* k = qkv + base + EE;

  const float q1 = bf2f(q[0]), q2 = bf2f(q[64]);
  q[0]  = f2bf(q1 * c - q2 * sn);
  q[64] = f2bf(q2 * c + q1 * sn);
  const float k1 = bf2f(k[0]), k2 = bf2f(k[64]);
  k[0]  = f2bf(k1 * c - k2 * sn);
  k[64] = f2bf(k2 * c + k1 * sn);
}

// ---------------------------------------------------------------------------
// V transpose: qkv V slab [b][s][h][d] -> vt [b*H+h][d][s]   (bf16)
// ---------------------------------------------------------------------------
__global__ __launch_bounds__(256) void transpose_v(
    const unsigned short* __restrict__ qkv, unsigned short* __restrict__ vt) {
  __shared__ unsigned short T[64][72];
  const int t = threadIdx.x;
  const int s0 = blockIdx.x * 64;
  const int d0 = blockIdx.y * 64;
  const int bh = blockIdx.z;
  const int b = bh >> 4, h = bh & 15;
  {
    const int r = t >> 2, c = (t & 3) * 16;
    const unsigned short* src =
        qkv + ((size_t)b * SS + s0 + r) * FF + 2 * EE + h * DD + d0 + c;
    const uint4 u0 = *(const uint4*)src;
    const uint4 u1 = *(const uint4*)(src + 8);
    *(uint4*)&T[r][c] = u0;
    *(uint4*)&T[r][c + 8] = u1;
  }
  __syncthreads();
  {
    const int rr = t >> 2, cc = (t & 3) * 16;
    unsigned short vals[16];
#pragma unroll
    for (int j = 0; j < 16; ++j) vals[j] = T[cc + j][rr];
    unsigned short* dst =
        vt + (size_t)bh * DD * SS + (size_t)(d0 + rr) * SS + s0 + cc;
    *(uint4*)dst = *(uint4*)&vals[0];
    *(uint4*)(dst + 8) = *(uint4*)&vals[8];
  }
}

// ---------------------------------------------------------------------------
// MFMA flash attention, causal (unchanged).
// ---------------------------------------------------------------------------
#define ATQ 128
#define ATK 32
#define SPAD 40
#define NQT (SS / ATQ)

__global__ __launch_bounds__(256, 2) void attn_mfma(
    const unsigned short* __restrict__ qkv,
    const unsigned short* __restrict__ vt,
    unsigned short* __restrict__ ctx) {
  __shared__ __align__(16) unsigned short Ksh[2][ATK * DD];
  __shared__ __align__(16) unsigned short Vsh[2][DD * ATK];
  __shared__ __align__(16) unsigned short Ssh[ATQ][SPAD];

  const int tid = threadIdx.x;
  const int L = tid & 63;
  const int w = tid >> 6;
  const int lane16 = L & 15;
  const int quad = L >> 4;

  const int flat = blockIdx.x;
  const int pi = flat >> 5;
  const int bh_lin = flat & 31;
  const int b = bh_lin >> 4;
  const int h = bh_lin & 15;
  const int bh = b * HH + h;
  const float scale = 0.08838834764831845f;

  size_t koff[2], voff[2];
  int kdst[2], vdst[2];
#pragma unroll
  for (int j = 0; j < 2; ++j) {
    const int ck = j * 256 + tid;
    const int kk = ck >> 4;
    const int cgk = (ck & 15) ^ (kk & 15);
    koff[j] = ((size_t)b * SS + kk) * FF + EE + h * DD + cgk * 8;
    kdst[j] = (j * 256 + w * 64) * 8;
    const int d = ck >> 2;
    const int cgv = (ck & 3) ^ (d & 3);
    voff[j] = (size_t)bh * DD * SS + (size_t)d * SS + cgv * 8;
    vdst[j] = kdst[j];
  }

#pragma unroll 1
  for (int phase = 0; phase < 2; ++phase) {
    const int qb = phase ? pi : (NQT - 1 - pi);
    const int q0 = qb * ATQ;

    short8 qf[2][4];
#pragma unroll
    for (int mi = 0; mi < 2; ++mi) {
      const int q = q0 + w * 32 + mi * 16 + lane16;
      const unsigned short* qp =
          qkv + ((size_t)b * SS + q) * FF + h * DD + quad * 8;
#pragma unroll
      for (int dc = 0; dc < 4; ++dc)
        qf[mi][dc] = *(const short8*)(qp + dc * 32);
    }

    floatx4 acc[8][2] = {};
    float m_i[2] = {-3.0e38f, -3.0e38f};
    float l_i[2] = {0.0f, 0.0f};

    const int nkt = 4 * qb + 4;
    const int mykt = 4 * qb + w;

#pragma unroll
    for (int j = 0; j < 2; ++j) {
      GLOAD_LDS16(qkv + koff[j], &Ksh[0][kdst[j]]);
      GLOAD_LDS16(vt + voff[j], &Vsh[0][vdst[j]]);
    }

    for (int kt = 0; kt < nkt; ++kt) {
      const int cur = kt & 1;
      __syncthreads();
      if (kt + 1 < nkt) {
        const size_t ka = (size_t)(kt + 1) * ATK * FF;
        const int va = (kt + 1) * ATK;
#pragma unroll
        for (int j = 0; j < 2; ++j) {
          GLOAD_LDS16(qkv + koff[j] + ka, &Ksh[cur ^ 1][kdst[j]]);
          GLOAD_LDS16(vt + voff[j] + va, &Vsh[cur ^ 1][vdst[j]]);
        }
      }
      if (kt > mykt) continue;
      const int k0 = kt * ATK;
      const unsigned short* Kc = Ksh[cur];
      const unsigned short* Vc = Vsh[cur];

      floatx4 st[2][2] = {};
#pragma unroll
      for (int kkt = 0; kkt < 2; ++kkt) {
        const unsigned short* krow = Kc + (kkt * 16 + lane16) * 128;
#pragma unroll
        for (int dc = 0; dc < 4; ++dc) {
          const short8 kf =
              *(const short8*)(krow + ((dc * 4 + quad) ^ lane16) * 8);
#pragma unroll
          for (int mi = 0; mi < 2; ++mi)
            st[kkt][mi] = __builtin_amdgcn_mfma_f32_16x16x32_bf16(
                kf, qf[mi][dc], st[kkt][mi], 0, 0, 0);
        }
      }

      const bool needmask = (kt == mykt);
#pragma unroll
      for (int mi = 0; mi < 2; ++mi) {
        const int q_glob = q0 + w * 32 + mi * 16 + lane16;
#pragma unroll
        for (int kkt = 0; kkt < 2; ++kkt) {
          const int kkb = k0 + kkt * 16 + quad * 4;
#pragma unroll
          for (int r = 0; r < 4; ++r) {
            float v = st[kkt][mi][r] * scale;
            if (needmask && (kkb + r) > q_glob) v = -3.0e38f;
            st[kkt][mi][r] = v;
          }
        }
      }

      float alpha[2];
#pragma unroll
      for (int mi = 0; mi < 2; ++mi) {
        float tm = -3.0e38f;
#pragma unroll
        for (int kkt = 0; kkt < 2; ++kkt)
#pragma unroll
          for (int r = 0; r < 4; ++r) tm = fmaxf(tm, st[kkt][mi][r]);
        tm = fmaxf(tm, __shfl_xor(tm, 16));
        tm = fmaxf(tm, __shfl_xor(tm, 32));
        const float mn = fmaxf(m_i[mi], tm);
        alpha[mi] = __expf(m_i[mi] - mn);
        m_i[mi] = mn;

        float rs = 0.0f;
#pragma unroll
        for (int kkt = 0; kkt < 2; ++kkt)
#pragma unroll
          for (int r = 0; r < 4; ++r) {
            const float p = __expf(st[kkt][mi][r] - mn);
            st[kkt][mi][r] = p;
            rs += p;
          }
        rs += __shfl_xor(rs, 16);
        rs += __shfl_xor(rs, 32);
        l_i[mi] = l_i[mi] * alpha[mi] + rs;

#pragma unroll
        for (int kkt = 0; kkt < 2; ++kkt) {
          ushort4 pk;
          pk.x = f2bf(st[kkt][mi][0]);
          pk.y = f2bf(st[kkt][mi][1]);
          pk.z = f2bf(st[kkt][mi][2]);
          pk.w = f2bf(st[kkt][mi][3]);
          *(ushort4*)(&Ssh[w * 32 + mi * 16 + lane16][kkt * 16 + quad * 4]) =
              pk;
        }
      }

#pragma unroll
      for (int dt = 0; dt < 8; ++dt)
#pragma unroll
        for (int mi = 0; mi < 2; ++mi)
#pragma unroll
          for (int r = 0; r < 4; ++r) acc[dt][mi][r] *= alpha[mi];

      short8 pa[2];
#pragma unroll
      for (int mi = 0; mi < 2; ++mi)
        pa[mi] = *(const short8*)(&Ssh[w * 32 + mi * 16 + lane16][quad * 8]);
      const int vpos = (quad ^ (lane16 & 3)) * 8;
#pragma unroll
      for (int dt = 0; dt < 8; ++dt) {
        const short8 vf =
            *(const short8*)(Vc + (dt * 16 + lane16) * 32 + vpos);
#pragma unroll
        for (int mi = 0; mi < 2; ++mi)
          acc[dt][mi] = __builtin_amdgcn_mfma_f32_16x16x32_bf16(
              vf, pa[mi], acc[dt][mi], 0, 0, 0);
      }
    }

#pragma unroll
    for (int mi = 0; mi < 2; ++mi) {
      const float inv = 1.0f / l_i[mi];
      const int q = q0 + w * 32 + mi * 16 + lane16;
      unsigned short* op = ctx + ((size_t)b * SS + q) * EE + h * DD + quad * 4;
#pragma unroll
      for (int dt = 0; dt < 8; ++dt) {
        ushort4 o;
        o.x = f2bf(acc[dt][mi][0] * inv);
        o.y = f2bf(acc[dt][mi][1] * inv);
        o.z = f2bf(acc[dt][mi][2] * inv);
        o.w = f2bf(acc[dt][mi][3] * inv);
        *(ushort4*)(op + dt * 16) = o;
      }
    }
  }
}

// ---------------------------------------------------------------------------
// Launch
// ---------------------------------------------------------------------------
extern "C" void kernel_launch(void* const* d_in, const int* in_sizes, int n_in,
                              void* d_out, int out_size, void* d_ws,
                              size_t ws_size, hipStream_t stream) {
  const float* x    = (const float*)d_in[0];
  const float* wqkv = (const float*)d_in[1];
  const float* bqkv = (const float*)d_in[2];
  const float* wout = (const float*)d_in[3];
  const float* bout = (const float*)d_in[4];
  float* out = (float*)d_out;

  unsigned short* qkvb = (unsigned short*)d_ws;      // 25165824 elems
  unsigned short* xb   = qkvb + (size_t)25165824;    //  8388608
  unsigned short* wqb  = xb + (size_t)8388608;       // 12582912
  unsigned short* ctxb = wqb + (size_t)12582912;     //  8388608
  unsigned short* wob  = ctxb + (size_t)8388608;     //  4194304
  unsigned short* vtb  = wob + (size_t)4194304;      //  8388608

  const int M = BB * SS;  // 4096

  cast_f32_bf16<<<8192, 256, 0, stream>>>(x, xb, 2097152);
  cast_f32_bf16<<<12288, 256, 0, stream>>>(wqkv, wqb, 3145728);
  cast_f32_bf16<<<4096, 256, 0, stream>>>(wout, wob, 1048576);

  {
    // 256^2 8-phase: grid 16*24 = 384 (%8==0 for XCD swizzle)
    gemm256_8ph<unsigned short><<<dim3(384), 512, 0, stream>>>(
        xb, wqb, bqkv, qkvb, M, FF, EE);
  }
  {
    const int total = BB * SS * HH * 64;
    rotary_kernel<<<total / 256, 256, 0, stream>>>(qkvb);
  }
  {
    dim3 grid(SS / 64, DD / 64, BB * HH);
    transpose_v<<<grid, 256, 0, stream>>>(qkvb, vtb);
  }
  {
    attn_mfma<<<dim3(256), 256, 0, stream>>>(qkvb, vtb, ctxb);
  }
  {
    dim3 grid(EE / 128, M / 128);
    gemm_bf16_mfma<float><<<grid, 256, 0, stream>>>(
        ctxb, wob, bout, out, M, EE, EE);
  }
}

// Round 4
// 415.600 us; speedup vs baseline: 1.0897x; 1.0544x over previous
//
#include <hip/hip_runtime.h>
#include <math.h>

// Problem constants
#define BB 2
#define SS 2048
#define EE 2048
#define HH 16
#define DD 128
#define FF 6144   // 3*E

typedef __attribute__((ext_vector_type(8))) short short8;
typedef __attribute__((ext_vector_type(4))) float floatx4;

static __device__ __forceinline__ unsigned short f2bf(float x) {
  unsigned u = __float_as_uint(x);
  u += 0x7fffu + ((u >> 16) & 1u);
  return (unsigned short)(u >> 16);
}
static __device__ __forceinline__ float bf2f(unsigned short h) {
  return __uint_as_float((unsigned)h << 16);
}

#define GLOAD_LDS16(gp, lp)                                       \
  __builtin_amdgcn_global_load_lds(                               \
      (const __attribute__((address_space(1))) void*)(gp),        \
      (__attribute__((address_space(3))) void*)(lp), 16, 0, 0)

// ---------------------------------------------------------------------------
// fp32 -> bf16 cast (float4 in, ushort4 out)
// ---------------------------------------------------------------------------
__global__ __launch_bounds__(256) void cast_f32_bf16(
    const float* __restrict__ in, unsigned short* __restrict__ out, int n4) {
  const int i = blockIdx.x * 256 + threadIdx.x;
  if (i >= n4) return;
  const float4 v = ((const float4*)in)[i];
  ushort4 o;
  o.x = f2bf(v.x); o.y = f2bf(v.y); o.z = f2bf(v.z); o.w = f2bf(v.w);
  ((ushort4*)out)[i] = o;
}

static __device__ __forceinline__ void store_out(float* p, float v) { *p = v; }
static __device__ __forceinline__ void store_out(unsigned short* p, float v) {
  *p = f2bf(v);
}

// ---------------------------------------------------------------------------
// bf16 MFMA GEMM, double-buffered 128^2 (kept for the out-projection).
// ---------------------------------------------------------------------------
template <typename OutT>
__global__ __launch_bounds__(256) void gemm_bf16_mfma(
    const unsigned short* __restrict__ A, const unsigned short* __restrict__ Bt,
    const float* __restrict__ bias, OutT* __restrict__ C,
    int M, int N, int K) {
  __shared__ unsigned short As[2][128][32];
  __shared__ unsigned short Bs[2][128][32];
  const int tid = threadIdx.x;
  const int L = tid & 63;
  const int w = tid >> 6;
  const int m0 = blockIdx.y * 128;
  const int n0 = blockIdx.x * 128;

  const int i0 = w * 2;
  const int lrow = L >> 2;
  const int lcol = (L & 3) * 8;
  const size_t a_off0 = (size_t)(m0 + (i0 + 0) * 16 + lrow) * K + lcol;
  const size_t a_off1 = (size_t)(m0 + (i0 + 1) * 16 + lrow) * K + lcol;
  const size_t b_off0 = (size_t)(n0 + (i0 + 0) * 16 + lrow) * K + lcol;
  const size_t b_off1 = (size_t)(n0 + (i0 + 1) * 16 + lrow) * K + lcol;

  const int wr = (w >> 1) * 64;
  const int wc = (w & 1) * 64;
  const int lane16 = L & 15;
  const int quad = L >> 4;

  floatx4 acc[4][4] = {};

  GLOAD_LDS16(A + a_off0, &As[0][(i0 + 0) * 16][0]);
  GLOAD_LDS16(A + a_off1, &As[0][(i0 + 1) * 16][0]);
  GLOAD_LDS16(Bt + b_off0, &Bs[0][(i0 + 0) * 16][0]);
  GLOAD_LDS16(Bt + b_off1, &Bs[0][(i0 + 1) * 16][0]);

  for (int k0 = 0; k0 < K; k0 += 32) {
    const int cur = (k0 >> 5) & 1;
    __syncthreads();
    if (k0 + 32 < K) {
      const int nxt = cur ^ 1;
      GLOAD_LDS16(A + a_off0 + k0 + 32, &As[nxt][(i0 + 0) * 16][0]);
      GLOAD_LDS16(A + a_off1 + k0 + 32, &As[nxt][(i0 + 1) * 16][0]);
      GLOAD_LDS16(Bt + b_off0 + k0 + 32, &Bs[nxt][(i0 + 0) * 16][0]);
      GLOAD_LDS16(Bt + b_off1 + k0 + 32, &Bs[nxt][(i0 + 1) * 16][0]);
    }

    short8 a[4], b[4];
#pragma unroll
    for (int mi = 0; mi < 4; ++mi)
      a[mi] = *(const short8*)(&As[cur][wr + mi * 16 + lane16][quad * 8]);
#pragma unroll
    for (int ni = 0; ni < 4; ++ni)
      b[ni] = *(const short8*)(&Bs[cur][wc + ni * 16 + lane16][quad * 8]);
#pragma unroll
    for (int mi = 0; mi < 4; ++mi)
#pragma unroll
      for (int ni = 0; ni < 4; ++ni)
        acc[mi][ni] = __builtin_amdgcn_mfma_f32_16x16x32_bf16(
            a[mi], b[ni], acc[mi][ni], 0, 0, 0);
  }

#pragma unroll
  for (int ni = 0; ni < 4; ++ni) {
    const int col = n0 + wc + ni * 16 + lane16;
    const float bv = bias[col];
#pragma unroll
    for (int mi = 0; mi < 4; ++mi) {
      const int row = m0 + wr + mi * 16 + quad * 4;
#pragma unroll
      for (int r = 0; r < 4; ++r)
        store_out(&C[(size_t)(row + r) * N + col], acc[mi][ni][r] + bv);
    }
  }
}

// ---------------------------------------------------------------------------
// 256x192 bf16 GEMM (BK=64), grid-balanced: M/256 x N/192 = 16 x 32 = 512
// blocks = EXACTLY 2 full scheduling rounds on 256 CUs (the 256^2 kernel's
// 384 blocks were 1.5 rounds -> 75% packing; this is the dominant fix).
// 8 waves (2M x 4N), per-wave C = 128x48 (acc 96 VGPR). LDS = 112 KiB:
//   As[2][256*64], Bs[2][192*64], st_16x32 swizzle both sides (rule #21),
//   natural 64-row windows (window = 8KB = one gload_lds per wave).
// 2 relaxed phases per K-tile (1 barrier each):
//   P0: read a(lo half, 8) + b(all, 6); stage A(t+1)->As[c^1] (4); 24 MFMA
//   P1: read a(hi half, 8);             stage B(t+2)->Bs[c]   (3); 24 MFMA
//       vmcnt(3)  [drains A(t+1) + all older; leaves B(t+2) in flight]
// Write-after-read: A(t+1) overwrites As[c^1] whose last reads were [t-1,P1]
// (consumed pre-barrier); B(t+2) overwrites Bs[c]'s B, dead after [t,P0].
// Loads keep >=2-phase (~1400 cy) slack; never drained to 0.
// Tail stages read <=128 ushorts past the matrix end -> next ws buffer
// (allocated), land in dead LDS windows.
// ---------------------------------------------------------------------------
template <typename OutT>
__global__ __launch_bounds__(512, 2) void gemm_bf16_256x192(
    const unsigned short* __restrict__ A, const unsigned short* __restrict__ Bt,
    const float* __restrict__ bias, OutT* __restrict__ C,
    int M, int N, int K) {
  __shared__ __align__(16) unsigned short As[2][16384];  // 256x64
  __shared__ __align__(16) unsigned short Bs[2][12288];  // 192x64

  const int tid = threadIdx.x;
  const int w = tid >> 6;
  const int L = tid & 63;
  const int lane16 = L & 15;
  const int quad = L >> 4;
  const int wm = w >> 2;   // 0..1
  const int wn = w & 3;    // 0..3

  // XCD-aware bijective swizzle, column-major chunks: each XCD owns 4
  // B-panel columns (4*192*2048*2B = 3 MB -> L2-resident).
  const int nby = M >> 8;          // 16
  const int q8 = gridDim.x >> 3;   // 64
  const int wg = (blockIdx.x & 7) * q8 + (blockIdx.x >> 3);
  const int by = wg % nby;
  const int bx = wg / nby;
  const int m0 = by << 8;
  const int n0 = bx * 192;

  // ---- staging source offsets (pre-swizzled global, rule #21) ----
  // window = 64 rows x 64 cols = 8KB; wave w stages subtile w:
  // rows (w>>1)*16 + (L>>2), col half (w&1), st_16x32 XOR on row bit3.
  const int lA = ((w >> 1) << 4) + (L >> 2);
  const int scol = ((w & 1) << 5) + (((L & 3) * 8) ^ ((L & 32) ? 16 : 0));
  unsigned aoff[4], boff[3];
#pragma unroll
  for (int j = 0; j < 4; ++j)
    aoff[j] = (unsigned)(m0 + j * 64 + lA) * (unsigned)K + scol;
#pragma unroll
  for (int j = 0; j < 3; ++j)
    boff[j] = (unsigned)(n0 + j * 64 + lA) * (unsigned)K + scol;
  const int ldst = w * 512;

  // ---- ds_read addressing (st_16x32 swizzle) ----
  const int sq = (quad * 8) ^ ((lane16 & 8) << 1);
  const int rbase = lane16 * 32 + sq;

  floatx4 acc[8][3] = {};

  // prologue: A0(4) -> As[0], B0(3) -> Bs[0], B1(3) -> Bs[1]
  GLOAD_LDS16(A + aoff[0], &As[0][0 * 4096 + ldst]);
  GLOAD_LDS16(A + aoff[1], &As[0][1 * 4096 + ldst]);
  GLOAD_LDS16(A + aoff[2], &As[0][2 * 4096 + ldst]);
  GLOAD_LDS16(A + aoff[3], &As[0][3 * 4096 + ldst]);
  GLOAD_LDS16(Bt + boff[0], &Bs[0][0 * 4096 + ldst]);
  GLOAD_LDS16(Bt + boff[1], &Bs[0][1 * 4096 + ldst]);
  GLOAD_LDS16(Bt + boff[2], &Bs[0][2 * 4096 + ldst]);
  GLOAD_LDS16(Bt + boff[0] + 64, &Bs[1][0 * 4096 + ldst]);
  GLOAD_LDS16(Bt + boff[1] + 64, &Bs[1][1 * 4096 + ldst]);
  GLOAD_LDS16(Bt + boff[2] + 64, &Bs[1][2 * 4096 + ldst]);
  asm volatile("s_waitcnt vmcnt(3)" ::: "memory");
  __builtin_amdgcn_sched_barrier(0);
  __builtin_amdgcn_s_barrier();

  const int NT = K >> 6;  // 32
  short8 a[4][2], b[3][2];

  for (int t = 0; t < NT; ++t) {
    const int c = t & 1;
    const unsigned kn1 = (unsigned)(t + 1) << 6;
    const unsigned kn2 = (unsigned)(t + 2) << 6;
    const unsigned short* Ac = &As[c][0];
    const unsigned short* Bc = &Bs[c][0];

    // ---------------- P0: read a-lo(8) + b(6); stage A(t+1); 24 MFMA
#pragma unroll
    for (int mi = 0; mi < 4; ++mi)
#pragma unroll
      for (int kk = 0; kk < 2; ++kk)
        a[mi][kk] = *(const short8*)(Ac + (wm * 2) * 4096 +
                                     ((mi * 2 + kk) * 512) + rbase);
#pragma unroll
    for (int ni = 0; ni < 3; ++ni) {
      const int f = wn * 3 + ni;
#pragma unroll
      for (int kk = 0; kk < 2; ++kk)
        b[ni][kk] = *(const short8*)(Bc + (f >> 2) * 4096 +
                                     (((f & 3) * 2 + kk) * 512) + rbase);
    }
    GLOAD_LDS16(A + aoff[0] + kn1, &As[c ^ 1][0 * 4096 + ldst]);
    GLOAD_LDS16(A + aoff[1] + kn1, &As[c ^ 1][1 * 4096 + ldst]);
    GLOAD_LDS16(A + aoff[2] + kn1, &As[c ^ 1][2 * 4096 + ldst]);
    GLOAD_LDS16(A + aoff[3] + kn1, &As[c ^ 1][3 * 4096 + ldst]);
    __builtin_amdgcn_s_setprio(1);
#pragma unroll
    for (int mi = 0; mi < 4; ++mi)
#pragma unroll
      for (int ni = 0; ni < 3; ++ni)
#pragma unroll
        for (int kk = 0; kk < 2; ++kk)
          acc[mi][ni] = __builtin_amdgcn_mfma_f32_16x16x32_bf16(
              a[mi][kk], b[ni][kk], acc[mi][ni], 0, 0, 0);
    __builtin_amdgcn_s_setprio(0);
    __builtin_amdgcn_sched_barrier(0);
    __builtin_amdgcn_s_barrier();

    // ---------------- P1: read a-hi(8); stage B(t+2); 24 MFMA; vmcnt(3)
#pragma unroll
    for (int mi = 0; mi < 4; ++mi)
#pragma unroll
      for (int kk = 0; kk < 2; ++kk)
        a[mi][kk] = *(const short8*)(Ac + (wm * 2 + 1) * 4096 +
                                     ((mi * 2 + kk) * 512) + rbase);
    GLOAD_LDS16(Bt + boff[0] + kn2, &Bs[c][0 * 4096 + ldst]);
    GLOAD_LDS16(Bt + boff[1] + kn2, &Bs[c][1 * 4096 + ldst]);
    GLOAD_LDS16(Bt + boff[2] + kn2, &Bs[c][2 * 4096 + ldst]);
    __builtin_amdgcn_s_setprio(1);
#pragma unroll
    for (int mi = 0; mi < 4; ++mi)
#pragma unroll
      for (int ni = 0; ni < 3; ++ni)
#pragma unroll
        for (int kk = 0; kk < 2; ++kk)
          acc[4 + mi][ni] = __builtin_amdgcn_mfma_f32_16x16x32_bf16(
              a[mi][kk], b[ni][kk], acc[4 + mi][ni], 0, 0, 0);
    __builtin_amdgcn_s_setprio(0);
    asm volatile("s_waitcnt vmcnt(3)" ::: "memory");
    __builtin_amdgcn_sched_barrier(0);
    __builtin_amdgcn_s_barrier();
  }

  // epilogue
#pragma unroll
  for (int ni = 0; ni < 3; ++ni) {
    const int col = n0 + wn * 48 + ni * 16 + lane16;
    const float bv = bias[col];
#pragma unroll
    for (int mi = 0; mi < 8; ++mi) {
      const int row = m0 + wm * 128 + mi * 16 + quad * 4;
#pragma unroll
      for (int r = 0; r < 4; ++r)
        store_out(&C[(size_t)(row + r) * N + col], acc[mi][ni][r] + bv);
    }
  }
}

// ---------------------------------------------------------------------------
// Rotary on bf16 qkv in place. qkv layout [B][S][3][H][D] bf16.
// ---------------------------------------------------------------------------
__global__ __launch_bounds__(256) void rotary_kernel(unsigned short* __restrict__ qkv) {
  const int idx = blockIdx.x * blockDim.x + threadIdx.x;
  const int d = idx & 63;
  const int h = (idx >> 6) & (HH - 1);
  const int s = (idx >> 10) & (SS - 1);
  const int b = idx >> 21;

  const float inv_freq = __expf(-(float)d * 0.14391156509f);
  float sn, c;
  __sincosf((float)s * inv_freq, &sn, &c);

  const size_t base = ((size_t)b * SS + s) * FF + h * DD + d;
  unsigned short* q = qkv + base;
  unsigned short* k = qkv + base + EE;

  const float q1 = bf2f(q[0]), q2 = bf2f(q[64]);
  q[0]  = f2bf(q1 * c - q2 * sn);
  q[64] = f2bf(q2 * c + q1 * sn);
  const float k1 = bf2f(k[0]), k2 = bf2f(k[64]);
  k[0]  = f2bf(k1 * c - k2 * sn);
  k[64] = f2bf(k2 * c + k1 * sn);
}

// ---------------------------------------------------------------------------
// V transpose: qkv V slab [b][s][h][d] -> vt [b*H+h][d][s]   (bf16)
// ---------------------------------------------------------------------------
__global__ __launch_bounds__(256) void transpose_v(
    const unsigned short* __restrict__ qkv, unsigned short* __restrict__ vt) {
  __shared__ unsigned short T[64][72];
  const int t = threadIdx.x;
  const int s0 = blockIdx.x * 64;
  const int d0 = blockIdx.y * 64;
  const int bh = blockIdx.z;
  const int b = bh >> 4, h = bh & 15;
  {
    const int r = t >> 2, c = (t & 3) * 16;
    const unsigned short* src =
        qkv + ((size_t)b * SS + s0 + r) * FF + 2 * EE + h * DD + d0 + c;
    const uint4 u0 = *(const uint4*)src;
    const uint4 u1 = *(const uint4*)(src + 8);
    *(uint4*)&T[r][c] = u0;
    *(uint4*)&T[r][c + 8] = u1;
  }
  __syncthreads();
  {
    const int rr = t >> 2, cc = (t & 3) * 16;
    unsigned short vals[16];
#pragma unroll
    for (int j = 0; j < 16; ++j) vals[j] = T[cc + j][rr];
    unsigned short* dst =
        vt + (size_t)bh * DD * SS + (size_t)(d0 + rr) * SS + s0 + cc;
    *(uint4*)dst = *(uint4*)&vals[0];
    *(uint4*)(dst + 8) = *(uint4*)&vals[8];
  }
}

// ---------------------------------------------------------------------------
// MFMA flash attention, causal (unchanged).
// ---------------------------------------------------------------------------
#define ATQ 128
#define ATK 32
#define SPAD 40
#define NQT (SS / ATQ)

__global__ __launch_bounds__(256, 2) void attn_mfma(
    const unsigned short* __restrict__ qkv,
    const unsigned short* __restrict__ vt,
    unsigned short* __restrict__ ctx) {
  __shared__ __align__(16) unsigned short Ksh[2][ATK * DD];
  __shared__ __align__(16) unsigned short Vsh[2][DD * ATK];
  __shared__ __align__(16) unsigned short Ssh[ATQ][SPAD];

  const int tid = threadIdx.x;
  const int L = tid & 63;
  const int w = tid >> 6;
  const int lane16 = L & 15;
  const int quad = L >> 4;

  const int flat = blockIdx.x;
  const int pi = flat >> 5;
  const int bh_lin = flat & 31;
  const int b = bh_lin >> 4;
  const int h = bh_lin & 15;
  const int bh = b * HH + h;
  const float scale = 0.08838834764831845f;

  size_t koff[2], voff[2];
  int kdst[2], vdst[2];
#pragma unroll
  for (int j = 0; j < 2; ++j) {
    const int ck = j * 256 + tid;
    const int kk = ck >> 4;
    const int cgk = (ck & 15) ^ (kk & 15);
    koff[j] = ((size_t)b * SS + kk) * FF + EE + h * DD + cgk * 8;
    kdst[j] = (j * 256 + w * 64) * 8;
    const int d = ck >> 2;
    const int cgv = (ck & 3) ^ (d & 3);
    voff[j] = (size_t)bh * DD * SS + (size_t)d * SS + cgv * 8;
    vdst[j] = kdst[j];
  }

#pragma unroll 1
  for (int phase = 0; phase < 2; ++phase) {
    const int qb = phase ? pi : (NQT - 1 - pi);
    const int q0 = qb * ATQ;

    short8 qf[2][4];
#pragma unroll
    for (int mi = 0; mi < 2; ++mi) {
      const int q = q0 + w * 32 + mi * 16 + lane16;
      const unsigned short* qp =
          qkv + ((size_t)b * SS + q) * FF + h * DD + quad * 8;
#pragma unroll
      for (int dc = 0; dc < 4; ++dc)
        qf[mi][dc] = *(const short8*)(qp + dc * 32);
    }

    floatx4 acc[8][2] = {};
    float m_i[2] = {-3.0e38f, -3.0e38f};
    float l_i[2] = {0.0f, 0.0f};

    const int nkt = 4 * qb + 4;
    const int mykt = 4 * qb + w;

#pragma unroll
    for (int j = 0; j < 2; ++j) {
      GLOAD_LDS16(qkv + koff[j], &Ksh[0][kdst[j]]);
      GLOAD_LDS16(vt + voff[j], &Vsh[0][vdst[j]]);
    }

    for (int kt = 0; kt < nkt; ++kt) {
      const int cur = kt & 1;
      __syncthreads();
      if (kt + 1 < nkt) {
        const size_t ka = (size_t)(kt + 1) * ATK * FF;
        const int va = (kt + 1) * ATK;
#pragma unroll
        for (int j = 0; j < 2; ++j) {
          GLOAD_LDS16(qkv + koff[j] + ka, &Ksh[cur ^ 1][kdst[j]]);
          GLOAD_LDS16(vt + voff[j] + va, &Vsh[cur ^ 1][vdst[j]]);
        }
      }
      if (kt > mykt) continue;
      const int k0 = kt * ATK;
      const unsigned short* Kc = Ksh[cur];
      const unsigned short* Vc = Vsh[cur];

      floatx4 st[2][2] = {};
#pragma unroll
      for (int kkt = 0; kkt < 2; ++kkt) {
        const unsigned short* krow = Kc + (kkt * 16 + lane16) * 128;
#pragma unroll
        for (int dc = 0; dc < 4; ++dc) {
          const short8 kf =
              *(const short8*)(krow + ((dc * 4 + quad) ^ lane16) * 8);
#pragma unroll
          for (int mi = 0; mi < 2; ++mi)
            st[kkt][mi] = __builtin_amdgcn_mfma_f32_16x16x32_bf16(
                kf, qf[mi][dc], st[kkt][mi], 0, 0, 0);
        }
      }

      const bool needmask = (kt == mykt);
#pragma unroll
      for (int mi = 0; mi < 2; ++mi) {
        const int q_glob = q0 + w * 32 + mi * 16 + lane16;
#pragma unroll
        for (int kkt = 0; kkt < 2; ++kkt) {
          const int kkb = k0 + kkt * 16 + quad * 4;
#pragma unroll
          for (int r = 0; r < 4; ++r) {
            float v = st[kkt][mi][r] * scale;
            if (needmask && (kkb + r) > q_glob) v = -3.0e38f;
            st[kkt][mi][r] = v;
          }
        }
      }

      float alpha[2];
#pragma unroll
      for (int mi = 0; mi < 2; ++mi) {
        float tm = -3.0e38f;
#pragma unroll
        for (int kkt = 0; kkt < 2; ++kkt)
#pragma unroll
          for (int r = 0; r < 4; ++r) tm = fmaxf(tm, st[kkt][mi][r]);
        tm = fmaxf(tm, __shfl_xor(tm, 16));
        tm = fmaxf(tm, __shfl_xor(tm, 32));
        const float mn = fmaxf(m_i[mi], tm);
        alpha[mi] = __expf(m_i[mi] - mn);
        m_i[mi] = mn;

        float rs = 0.0f;
#pragma unroll
        for (int kkt = 0; kkt < 2; ++kkt)
#pragma unroll
          for (int r = 0; r < 4; ++r) {
            const float p = __expf(st[kkt][mi][r] - mn);
            st[kkt][mi][r] = p;
            rs += p;
          }
        rs += __shfl_xor(rs, 16);
        rs += __shfl_xor(rs, 32);
        l_i[mi] = l_i[mi] * alpha[mi] + rs;

#pragma unroll
        for (int kkt = 0; kkt < 2; ++kkt) {
          ushort4 pk;
          pk.x = f2bf(st[kkt][mi][0]);
          pk.y = f2bf(st[kkt][mi][1]);
          pk.z = f2bf(st[kkt][mi][2]);
          pk.w = f2bf(st[kkt][mi][3]);
          *(ushort4*)(&Ssh[w * 32 + mi * 16 + lane16][kkt * 16 + quad * 4]) =
              pk;
        }
      }

#pragma unroll
      for (int dt = 0; dt < 8; ++dt)
#pragma unroll
        for (int mi = 0; mi < 2; ++mi)
#pragma unroll
          for (int r = 0; r < 4; ++r) acc[dt][mi][r] *= alpha[mi];

      short8 pa[2];
#pragma unroll
      for (int mi = 0; mi < 2; ++mi)
        pa[mi] = *(const short8*)(&Ssh[w * 32 + mi * 16 + lane16][quad * 8]);
      const int vpos = (quad ^ (lane16 & 3)) * 8;
#pragma unroll
      for (int dt = 0; dt < 8; ++dt) {
        const short8 vf =
            *(const short8*)(Vc + (dt * 16 + lane16) * 32 + vpos);
#pragma unroll
        for (int mi = 0; mi < 2; ++mi)
          acc[dt][mi] = __builtin_amdgcn_mfma_f32_16x16x32_bf16(
              vf, pa[mi], acc[dt][mi], 0, 0, 0);
      }
    }

#pragma unroll
    for (int mi = 0; mi < 2; ++mi) {
      const float inv = 1.0f / l_i[mi];
      const int q = q0 + w * 32 + mi * 16 + lane16;
      unsigned short* op = ctx + ((size_t)b * SS + q) * EE + h * DD + quad * 4;
#pragma unroll
      for (int dt = 0; dt < 8; ++dt) {
        ushort4 o;
        o.x = f2bf(acc[dt][mi][0] * inv);
        o.y = f2bf(acc[dt][mi][1] * inv);
        o.z = f2bf(acc[dt][mi][2] * inv);
        o.w = f2bf(acc[dt][mi][3] * inv);
        *(ushort4*)(op + dt * 16) = o;
      }
    }
  }
}

// ---------------------------------------------------------------------------
// Launch
// ---------------------------------------------------------------------------
extern "C" void kernel_launch(void* const* d_in, const int* in_sizes, int n_in,
                              void* d_out, int out_size, void* d_ws,
                              size_t ws_size, hipStream_t stream) {
  const float* x    = (const float*)d_in[0];
  const float* wqkv = (const float*)d_in[1];
  const float* bqkv = (const float*)d_in[2];
  const float* wout = (const float*)d_in[3];
  const float* bout = (const float*)d_in[4];
  float* out = (float*)d_out;

  unsigned short* qkvb = (unsigned short*)d_ws;      // 25165824 elems
  unsigned short* xb   = qkvb + (size_t)25165824;    //  8388608
  unsigned short* wqb  = xb + (size_t)8388608;       // 12582912
  unsigned short* ctxb = wqb + (size_t)12582912;     //  8388608
  unsigned short* wob  = ctxb + (size_t)8388608;     //  4194304
  unsigned short* vtb  = wob + (size_t)4194304;      //  8388608

  const int M = BB * SS;  // 4096

  cast_f32_bf16<<<8192, 256, 0, stream>>>(x, xb, 2097152);
  cast_f32_bf16<<<12288, 256, 0, stream>>>(wqkv, wqb, 3145728);
  cast_f32_bf16<<<4096, 256, 0, stream>>>(wout, wob, 1048576);

  {
    // 256x192 balanced grid: 16 x 32 = 512 blocks = exactly 2 rounds
    gemm_bf16_256x192<unsigned short><<<dim3(512), 512, 0, stream>>>(
        xb, wqb, bqkv, qkvb, M, FF, EE);
  }
  {
    const int total = BB * SS * HH * 64;
    rotary_kernel<<<total / 256, 256, 0, stream>>>(qkvb);
  }
  {
    dim3 grid(SS / 64, DD / 64, BB * HH);
    transpose_v<<<grid, 256, 0, stream>>>(qkvb, vtb);
  }
  {
    attn_mfma<<<dim3(256), 256, 0, stream>>>(qkvb, vtb, ctxb);
  }
  {
    dim3 grid(EE / 128, M / 128);
    gemm_bf16_mfma<float><<<grid, 256, 0, stream>>>(
        ctxb, wob, bout, out, M, EE, EE);
  }
}